// Round 1
// baseline (919.700 us; speedup 1.0000x reference)
//
#include <hip/hip_runtime.h>
#include <math.h>

#define NRES 512
#define CSD  384
#define CZD  128
#define HD   12

// workspace layout (float offsets)
#define OFF_Q    0
#define OFF_K    98304
#define OFF_V    196608
#define OFF_QP   294912
#define OFF_KP   368640
#define OFF_VP   442368
#define OFF_BIAS 589824
#define OFF_OCAT 3735552
#define OFF_PART 4816896   // 8 * 196608 floats

#define NT1 4  // n-tile for k_proj

// ---------------------------------------------------------------- projections
__global__ __launch_bounds__(256) void k_proj(
    const float* __restrict__ s, const float* __restrict__ rot, const float* __restrict__ trans,
    const float* __restrict__ w_q, const float* __restrict__ b_q,
    const float* __restrict__ w_kv, const float* __restrict__ b_kv,
    const float* __restrict__ w_qp, const float* __restrict__ b_qp,
    const float* __restrict__ w_kvp, const float* __restrict__ b_kvp,
    float* __restrict__ q, float* __restrict__ kk, float* __restrict__ vv,
    float* __restrict__ q_pts, float* __restrict__ k_pts, float* __restrict__ v_pts)
{
    const int n0 = blockIdx.x * NT1;
    const int t = threadIdx.x;
    __shared__ float s_lds[NT1][CSD];
    __shared__ float proj[NT1][1152];

    for (int i = t; i < NT1*CSD; i += 256) s_lds[i/CSD][i%CSD] = s[n0*CSD + i];
    __syncthreads();

    for (int u = t; u < 1152; u += 256) {
        const float *w, *b; int col, od;
        if (u < 192)      { w = w_q;   b = b_q;   col = u;       od = 192; }
        else if (u < 576) { w = w_kv;  b = b_kv;  col = u - 192; od = 384; }
        else if (u < 720) { w = w_qp;  b = b_qp;  col = u - 576; od = 144; }
        else              { w = w_kvp; b = b_kvp; col = u - 720; od = 432; }
        float acc0 = b[col], acc1 = acc0, acc2 = acc0, acc3 = acc0;
        for (int i = 0; i < CSD; ++i) {
            float wv_ = w[i*od + col];
            acc0 += s_lds[0][i] * wv_;
            acc1 += s_lds[1][i] * wv_;
            acc2 += s_lds[2][i] * wv_;
            acc3 += s_lds[3][i] * wv_;
        }
        proj[0][u] = acc0; proj[1][u] = acc1; proj[2][u] = acc2; proj[3][u] = acc3;
    }
    __syncthreads();

    for (int nn = 0; nn < NT1; ++nn) {
        const int n = n0 + nn;
        if (t < 192) q[n*192 + t] = proj[nn][t];
        for (int u = t; u < 384; u += 256) {
            int h = u >> 5, c = u & 31;
            float val = proj[nn][192 + u];
            if (c < 16) kk[n*192 + h*16 + c] = val;
            else        vv[n*192 + h*16 + c - 16] = val;
        }
        if (t < 192) {
            const float* R = rot + n*9;
            const float* T = trans + n*3;
            float px, py, pz;
            if (t < 48) {
                px = proj[nn][576 + t]; py = proj[nn][624 + t]; pz = proj[nn][672 + t];
            } else {
                int pt = t - 48;
                px = proj[nn][720 + pt]; py = proj[nn][864 + pt]; pz = proj[nn][1008 + pt];
            }
            float x  = R[0]*px + R[1]*py + R[2]*pz + T[0];
            float y  = R[3]*px + R[4]*py + R[5]*pz + T[1];
            float zc = R[6]*px + R[7]*py + R[8]*pz + T[2];
            if (t < 48) {
                int o = (n*48 + t)*3;
                q_pts[o] = x; q_pts[o+1] = y; q_pts[o+2] = zc;
            } else {
                int pt = t - 48;
                int h = pt / 12, pp = pt % 12;
                if (pp < 4) {
                    int o = (n*48 + h*4 + pp)*3;
                    k_pts[o] = x; k_pts[o+1] = y; k_pts[o+2] = zc;
                } else {
                    int o = (n*96 + h*8 + (pp-4))*3;
                    v_pts[o] = x; v_pts[o+1] = y; v_pts[o+2] = zc;
                }
            }
        }
    }
}

// ---------------------------------------------------------------- bias = z @ w_b + b_b
__global__ __launch_bounds__(256) void k_bias(
    const float* __restrict__ z, const float* __restrict__ w_b, const float* __restrict__ b_b,
    float* __restrict__ bias)
{
    const int qn = blockIdx.y;
    const int k0 = blockIdx.x * 64;
    const int t = threadIdx.x;
    __shared__ float zt[64*129];
    __shared__ float wb[128*12];
    __shared__ float part[4][64][13];

    for (int i = t; i < 1536; i += 256) wb[i] = w_b[i];
    const float4* zp4 = (const float4*)(z + ((size_t)qn*NRES + k0)*CZD);
    #pragma unroll
    for (int r = 0; r < 8; ++r) {
        int idx = t + r*256;            // float4 index in 64x128 tile
        int kx = idx >> 5, c4 = idx & 31;
        float4 v4 = zp4[idx];
        float* dst = &zt[kx*129 + c4*4];
        dst[0] = v4.x; dst[1] = v4.y; dst[2] = v4.z; dst[3] = v4.w;
    }
    __syncthreads();

    const int kx = t & 63, qr = t >> 6;
    float acc[12];
    #pragma unroll
    for (int h = 0; h < 12; ++h) acc[h] = 0.f;
    const float* zrow = &zt[kx*129 + qr*32];
    const float* wbp = &wb[qr*32*12];
    for (int c = 0; c < 32; ++c) {
        float zv = zrow[c];
        #pragma unroll
        for (int h = 0; h < 12; ++h) acc[h] += zv * wbp[c*12 + h];
    }
    #pragma unroll
    for (int h = 0; h < 12; ++h) part[qr][kx][h] = acc[h];
    __syncthreads();

    for (int d = t; d < 768; d += 256) {
        int k2 = d / 12, h = d % 12;
        float b = b_b[h] + part[0][k2][h] + part[1][k2][h] + part[2][k2][h] + part[3][k2][h];
        bias[((size_t)qn*NRES + k0 + k2)*12 + h] = b;
    }
}

// ---------------------------------------------------------------- fused attention per q-row
__global__ __launch_bounds__(256) void k_attn(
    const float* __restrict__ z,
    const float* __restrict__ q, const float* __restrict__ kk, const float* __restrict__ vv,
    const float* __restrict__ q_pts, const float* __restrict__ k_pts, const float* __restrict__ v_pts,
    const float* __restrict__ bias, const float* __restrict__ head_weights,
    const float* __restrict__ mask, const float* __restrict__ rot, const float* __restrict__ trans,
    float* __restrict__ o_cat)
{
    const int qn = blockIdx.x;
    const int t = threadIdx.x;
    const int lane = t & 63, wv = t >> 6;
    __shared__ float a_lds[12][520];
    __shared__ float q_lds[192];
    __shared__ float qp_lds[144];
    __shared__ float hw_lds[12];
    __shared__ float red[4];
    __shared__ float optraw[288];

    for (int i = t; i < 192; i += 256) q_lds[i] = q[qn*192 + i];
    for (int i = t; i < 144; i += 256) qp_lds[i] = q_pts[qn*144 + i];
    if (t < 12) {
        float x = head_weights[t];
        hw_lds[t] = logf(1.f + expf(x)) * 0.13608276f;  // softplus * sqrt(1/54)
    }
    __syncthreads();

    // ---- logits
    const float mq = mask[qn];
    for (int kn = t; kn < NRES; kn += 256) {
        const float mterm = (mq * mask[kn] - 1.f) * 100000.f;
        const float* kp  = kk + kn*192;
        const float* kpt = k_pts + kn*144;
        const float* bp  = bias + ((size_t)qn*NRES + kn)*12;
        #pragma unroll 1
        for (int h = 0; h < 12; ++h) {
            float acc = 0.f;
            #pragma unroll
            for (int c = 0; c < 16; ++c) acc += q_lds[h*16+c] * kp[h*16+c];
            acc *= 0.14433757f;            // sqrt(1/48)
            acc += 0.57735027f * bp[h];    // sqrt(1/3) * bias
            float dsum = 0.f;
            #pragma unroll
            for (int p = 0; p < 4; ++p) {
                int o = (h*4 + p)*3;
                float dx = qp_lds[o]   - kpt[o];
                float dy = qp_lds[o+1] - kpt[o+1];
                float dz = qp_lds[o+2] - kpt[o+2];
                dsum += dx*dx + dy*dy + dz*dz;
            }
            a_lds[h][kn] = acc - 0.5f * hw_lds[h] * dsum + mterm;
        }
    }
    __syncthreads();

    // ---- softmax (exact, per head)
    for (int h = 0; h < 12; ++h) {
        float m = -1e30f;
        for (int kn = t; kn < NRES; kn += 256) m = fmaxf(m, a_lds[h][kn]);
        #pragma unroll
        for (int off = 32; off > 0; off >>= 1) m = fmaxf(m, __shfl_xor(m, off));
        if (lane == 0) red[wv] = m;
        __syncthreads();
        m = fmaxf(fmaxf(red[0], red[1]), fmaxf(red[2], red[3]));
        __syncthreads();
        float ssum = 0.f;
        for (int kn = t; kn < NRES; kn += 256) {
            float e = __expf(a_lds[h][kn] - m);
            a_lds[h][kn] = e;
            ssum += e;
        }
        #pragma unroll
        for (int off = 32; off > 0; off >>= 1) ssum += __shfl_xor(ssum, off);
        if (lane == 0) red[wv] = ssum;
        __syncthreads();
        float inv = 1.f / (red[0] + red[1] + red[2] + red[3]);
        for (int kn = t; kn < NRES; kn += 256) a_lds[h][kn] *= inv;
        __syncthreads();
    }

    // ---- o_pair: second z pass (coalesced float2 per lane), 3 heads per wave
    {
        const int hgrp = t >> 6, c2 = t & 63;
        const int h0 = hgrp*3;
        const float2* zp = (const float2*)(z + (size_t)qn*NRES*CZD) + c2;
        float acc0=0.f,acc1=0.f,acc2=0.f,acc3=0.f,acc4=0.f,acc5=0.f;
        for (int kn = 0; kn < NRES; ++kn) {
            float2 zv = zp[(size_t)kn*64];
            float a0 = a_lds[h0][kn], a1 = a_lds[h0+1][kn], a2 = a_lds[h0+2][kn];
            acc0 += a0*zv.x; acc1 += a0*zv.y;
            acc2 += a1*zv.x; acc3 += a1*zv.y;
            acc4 += a2*zv.x; acc5 += a2*zv.y;
        }
        float* ob = o_cat + qn*2112 + 576;
        ob[(h0+0)*128 + 2*c2] = acc0; ob[(h0+0)*128 + 2*c2 + 1] = acc1;
        ob[(h0+1)*128 + 2*c2] = acc2; ob[(h0+1)*128 + 2*c2 + 1] = acc3;
        ob[(h0+2)*128 + 2*c2] = acc4; ob[(h0+2)*128 + 2*c2 + 1] = acc5;
    }

    // ---- o (192) and o_pt raw (288)
    for (int u = t; u < 480; u += 256) {
        float acc = 0.f;
        if (u < 192) {
            const float* vp = vv + u;
            const float* ap = a_lds[u >> 4];
            for (int kn = 0; kn < NRES; ++kn) acc += ap[kn] * vp[kn*192];
            o_cat[qn*2112 + u] = acc;
        } else {
            int u2 = u - 192;
            const float* vp = v_pts + u2;
            const float* ap = a_lds[u2 / 24];
            for (int kn = 0; kn < NRES; ++kn) acc += ap[kn] * vp[kn*288];
            optraw[u2] = acc;
        }
    }
    __syncthreads();

    // ---- inverse rotation + norms
    if (t < 96) {
        const float* R = rot + qn*9;
        const float* T = trans + qn*3;
        float ox = optraw[t*3]   - T[0];
        float oy = optraw[t*3+1] - T[1];
        float oz = optraw[t*3+2] - T[2];
        float x  = R[0]*ox + R[3]*oy + R[6]*oz;   // R^T (einsum bnji)
        float y  = R[1]*ox + R[4]*oy + R[7]*oz;
        float zc = R[2]*ox + R[5]*oy + R[8]*oz;
        float* ob = o_cat + qn*2112;
        ob[192 + t] = x;
        ob[288 + t] = y;
        ob[384 + t] = zc;
        ob[480 + t] = sqrtf(x*x + y*y + zc*zc + 1e-8f);
    }
}

// ---------------------------------------------------------------- final GEMM (d-chunked, deterministic)
__global__ __launch_bounds__(384) void k_out(
    const float* __restrict__ o_cat, const float* __restrict__ w_out, float* __restrict__ part)
{
    const int dc = blockIdx.x;       // 0..7, 264 d's each
    const int n0 = blockIdx.y * 8;   // n-tile
    const int t = threadIdx.x;       // 384 = output column
    float acc[8];
    #pragma unroll
    for (int nn = 0; nn < 8; ++nn) acc[nn] = 0.f;
    const int d0 = dc * 264;
    for (int d = d0; d < d0 + 264; ++d) {
        float w = w_out[d*384 + t];
        #pragma unroll
        for (int nn = 0; nn < 8; ++nn) acc[nn] += o_cat[(n0+nn)*2112 + d] * w;
    }
    #pragma unroll
    for (int nn = 0; nn < 8; ++nn) part[dc*196608 + (n0+nn)*384 + t] = acc[nn];
}

__global__ __launch_bounds__(256) void k_red(
    const float* __restrict__ part, const float* __restrict__ b_out, float* __restrict__ out)
{
    const int i = blockIdx.x*256 + threadIdx.x;  // < 196608
    float acc = b_out[i % 384];
    #pragma unroll
    for (int dc = 0; dc < 8; ++dc) acc += part[dc*196608 + i];
    out[i] = acc;
}

// ----------------------------------------------------------------
extern "C" void kernel_launch(void* const* d_in, const int* in_sizes, int n_in,
                              void* d_out, int out_size, void* d_ws, size_t ws_size,
                              hipStream_t stream) {
    (void)in_sizes; (void)n_in; (void)out_size; (void)ws_size;
    const float* s      = (const float*)d_in[0];
    const float* z      = (const float*)d_in[1];
    const float* rot    = (const float*)d_in[2];
    const float* trans  = (const float*)d_in[3];
    const float* mask   = (const float*)d_in[4];
    const float* w_q    = (const float*)d_in[5];
    const float* b_q    = (const float*)d_in[6];
    const float* w_kv   = (const float*)d_in[7];
    const float* b_kv   = (const float*)d_in[8];
    const float* w_qp   = (const float*)d_in[9];
    const float* b_qp   = (const float*)d_in[10];
    const float* w_kvp  = (const float*)d_in[11];
    const float* b_kvp  = (const float*)d_in[12];
    const float* w_b    = (const float*)d_in[13];
    const float* b_b    = (const float*)d_in[14];
    const float* hwts   = (const float*)d_in[15];
    const float* w_out  = (const float*)d_in[16];
    const float* b_out  = (const float*)d_in[17];
    float* out = (float*)d_out;
    float* ws  = (float*)d_ws;

    float* q    = ws + OFF_Q;
    float* kk   = ws + OFF_K;
    float* vv   = ws + OFF_V;
    float* qp   = ws + OFF_QP;
    float* kp   = ws + OFF_KP;
    float* vp   = ws + OFF_VP;
    float* bias = ws + OFF_BIAS;
    float* ocat = ws + OFF_OCAT;
    float* part = ws + OFF_PART;

    k_proj<<<dim3(NRES/NT1), dim3(256), 0, stream>>>(s, rot, trans,
        w_q, b_q, w_kv, b_kv, w_qp, b_qp, w_kvp, b_kvp, q, kk, vv, qp, kp, vp);
    k_bias<<<dim3(8, NRES), dim3(256), 0, stream>>>(z, w_b, b_b, bias);
    k_attn<<<dim3(NRES), dim3(256), 0, stream>>>(z, q, kk, vv, qp, kp, vp,
        bias, hwts, mask, rot, trans, ocat);
    k_out<<<dim3(8, 64), dim3(384), 0, stream>>>(ocat, w_out, part);
    k_red<<<dim3(768), dim3(256), 0, stream>>>(part, b_out, out);
}

// Round 2
// 513.328 us; speedup vs baseline: 1.7916x; 1.7916x over previous
//
#include <hip/hip_runtime.h>
#include <math.h>

#define NRES 512
#define CSD  384
#define CZD  128
#define HD   12

// workspace layout (float offsets)
#define OFF_Q    0
#define OFF_K    98304
#define OFF_V    196608
#define OFF_QP   294912
#define OFF_KP   368640
#define OFF_VP   442368
#define OFF_BIAS 589824
#define OFF_OCAT 3735552
#define OFF_PART 4816896   // 8 * 196608 floats (also aliased by praw_* before k_out)

// ---------------------------------------------------------------- projections GEMM
// S(512x384) @ {w_q,w_kv,w_qp,w_kvp} with virtual 64-col tiling.
// grid = (19 col-tiles, 8 n-tiles), block = 256 (16x16 threads, 4x4 micro-tile)
__global__ __launch_bounds__(256) void k_proj(
    const float* __restrict__ s,
    const float* __restrict__ w_q, const float* __restrict__ b_q,
    const float* __restrict__ w_kv, const float* __restrict__ b_kv,
    const float* __restrict__ w_qp, const float* __restrict__ b_qp,
    const float* __restrict__ w_kvp, const float* __restrict__ b_kvp,
    float* __restrict__ q, float* __restrict__ kk, float* __restrict__ vv,
    float* __restrict__ praw_q, float* __restrict__ praw_kv)
{
    const int ct = blockIdx.x;
    const int n0 = blockIdx.y * 64;
    const int t = threadIdx.x;

    const float *w, *bias_p; int od, base, kind;
    if (ct < 3)       { kind=0; w=w_q;   bias_p=b_q;   od=192; base=ct*64; }
    else if (ct < 9)  { kind=1; w=w_kv;  bias_p=b_kv;  od=384; base=(ct-3)*64; }
    else if (ct < 12) { kind=2; w=w_qp;  bias_p=b_qp;  od=144; base=(ct-9)*64; }
    else              { kind=3; w=w_kvp; bias_p=b_kvp; od=432; base=(ct-12)*64; }
    const int valid = min(64, od - base);

    __shared__ float s_lds[64][33];
    __shared__ float w_lds[32][68];

    const int tr = t >> 4, tc = t & 15;
    const int r0 = tr * 4, c0 = tc * 4;
    float acc[4][4];
    #pragma unroll
    for (int i = 0; i < 4; ++i)
        #pragma unroll
        for (int j = 0; j < 4; ++j) acc[i][j] = 0.f;

    for (int k0 = 0; k0 < CSD; k0 += 32) {
        __syncthreads();
        #pragma unroll
        for (int idx = t; idx < 2048; idx += 256) {
            int r = idx >> 5, kx = idx & 31;
            s_lds[r][kx] = s[(n0 + r) * CSD + k0 + kx];
        }
        #pragma unroll
        for (int idx = t; idx < 2048; idx += 256) {
            int kx = idx >> 6, c = idx & 63;
            w_lds[kx][c] = (c < valid) ? w[(k0 + kx) * od + base + c] : 0.f;
        }
        __syncthreads();
        #pragma unroll
        for (int kx = 0; kx < 32; ++kx) {
            float4 bv = *(const float4*)&w_lds[kx][c0];
            float a0 = s_lds[r0+0][kx], a1 = s_lds[r0+1][kx];
            float a2 = s_lds[r0+2][kx], a3 = s_lds[r0+3][kx];
            acc[0][0] += a0*bv.x; acc[0][1] += a0*bv.y; acc[0][2] += a0*bv.z; acc[0][3] += a0*bv.w;
            acc[1][0] += a1*bv.x; acc[1][1] += a1*bv.y; acc[1][2] += a1*bv.z; acc[1][3] += a1*bv.w;
            acc[2][0] += a2*bv.x; acc[2][1] += a2*bv.y; acc[2][2] += a2*bv.z; acc[2][3] += a2*bv.w;
            acc[3][0] += a3*bv.x; acc[3][1] += a3*bv.y; acc[3][2] += a3*bv.z; acc[3][3] += a3*bv.w;
        }
    }

    #pragma unroll
    for (int i = 0; i < 4; ++i) {
        const int n = n0 + r0 + i;
        #pragma unroll
        for (int j = 0; j < 4; ++j) {
            const int c = c0 + j;
            if (c >= valid) continue;
            const int gcol = base + c;
            const float v = acc[i][j] + bias_p[gcol];
            if (kind == 0) {
                q[n*192 + gcol] = v;
            } else if (kind == 1) {
                int h = gcol >> 5, cc = gcol & 31;
                if (cc < 16) kk[n*192 + h*16 + cc] = v;
                else         vv[n*192 + h*16 + cc - 16] = v;
            } else if (kind == 2) {
                praw_q[n*144 + gcol] = v;
            } else {
                praw_kv[n*432 + gcol] = v;
            }
        }
    }
}

// ---------------------------------------------------------------- rigid-frame rotation of points
__global__ __launch_bounds__(256) void k_rot(
    const float* __restrict__ praw_q, const float* __restrict__ praw_kv,
    const float* __restrict__ rot, const float* __restrict__ trans,
    float* __restrict__ q_pts, float* __restrict__ k_pts, float* __restrict__ v_pts)
{
    const int idx = blockIdx.x * 256 + threadIdx.x;   // < 512*192
    const int n = idx / 192, u = idx % 192;
    const float* R = rot + n*9;
    const float* T = trans + n*3;
    float px, py, pz;
    if (u < 48) {
        px = praw_q[n*144 + u]; py = praw_q[n*144 + 48 + u]; pz = praw_q[n*144 + 96 + u];
    } else {
        int pt = u - 48;
        px = praw_kv[n*432 + pt]; py = praw_kv[n*432 + 144 + pt]; pz = praw_kv[n*432 + 288 + pt];
    }
    float x  = R[0]*px + R[1]*py + R[2]*pz + T[0];
    float y  = R[3]*px + R[4]*py + R[5]*pz + T[1];
    float zc = R[6]*px + R[7]*py + R[8]*pz + T[2];
    if (u < 48) {
        int o = (n*48 + u)*3;
        q_pts[o] = x; q_pts[o+1] = y; q_pts[o+2] = zc;
    } else {
        int pt = u - 48;
        int h = pt / 12, pp = pt % 12;
        if (pp < 4) {
            int o = (n*48 + h*4 + pp)*3;
            k_pts[o] = x; k_pts[o+1] = y; k_pts[o+2] = zc;
        } else {
            int o = (n*96 + h*8 + (pp-4))*3;
            v_pts[o] = x; v_pts[o+1] = y; v_pts[o+2] = zc;
        }
    }
}

// ---------------------------------------------------------------- bias = z @ w_b + b_b
__global__ __launch_bounds__(256) void k_bias(
    const float* __restrict__ z, const float* __restrict__ w_b, const float* __restrict__ b_b,
    float* __restrict__ bias)
{
    const int qn = blockIdx.y;
    const int k0 = blockIdx.x * 64;
    const int t = threadIdx.x;
    __shared__ float zt[64*129];
    __shared__ float wb[128*12];
    __shared__ float part[4][64][13];

    for (int i = t; i < 1536; i += 256) wb[i] = w_b[i];
    const float4* zp4 = (const float4*)(z + ((size_t)qn*NRES + k0)*CZD);
    #pragma unroll
    for (int r = 0; r < 8; ++r) {
        int idx = t + r*256;            // float4 index in 64x128 tile
        int kx = idx >> 5, c4 = idx & 31;
        float4 v4 = zp4[idx];
        float* dst = &zt[kx*129 + c4*4];
        dst[0] = v4.x; dst[1] = v4.y; dst[2] = v4.z; dst[3] = v4.w;
    }
    __syncthreads();

    const int kx = t & 63, qr = t >> 6;
    float acc[12];
    #pragma unroll
    for (int h = 0; h < 12; ++h) acc[h] = 0.f;
    const float* zrow = &zt[kx*129 + qr*32];
    const float* wbp = &wb[qr*32*12];
    for (int c = 0; c < 32; ++c) {
        float zv = zrow[c];
        #pragma unroll
        for (int h = 0; h < 12; ++h) acc[h] += zv * wbp[c*12 + h];
    }
    #pragma unroll
    for (int h = 0; h < 12; ++h) part[qr][kx][h] = acc[h];
    __syncthreads();

    for (int d = t; d < 768; d += 256) {
        int k2 = d / 12, h = d % 12;
        float b = b_b[h] + part[0][k2][h] + part[1][k2][h] + part[2][k2][h] + part[3][k2][h];
        bias[((size_t)qn*NRES + k0 + k2)*12 + h] = b;
    }
}

// ---------------------------------------------------------------- fused attention per q-row
__global__ __launch_bounds__(256) void k_attn(
    const float* __restrict__ z,
    const float* __restrict__ q, const float* __restrict__ kk, const float* __restrict__ vv,
    const float* __restrict__ q_pts, const float* __restrict__ k_pts, const float* __restrict__ v_pts,
    const float* __restrict__ bias, const float* __restrict__ head_weights,
    const float* __restrict__ mask, const float* __restrict__ rot, const float* __restrict__ trans,
    float* __restrict__ o_cat)
{
    const int qn = blockIdx.x;
    const int t = threadIdx.x;
    const int lane = t & 63, wv = t >> 6;
    __shared__ float a_lds[12][520];
    __shared__ float q_lds[192];
    __shared__ float qp_lds[144];
    __shared__ float hw_lds[12];
    __shared__ float red[4];
    __shared__ float optraw[288];

    for (int i = t; i < 192; i += 256) q_lds[i] = q[qn*192 + i];
    for (int i = t; i < 144; i += 256) qp_lds[i] = q_pts[qn*144 + i];
    if (t < 12) {
        float x = head_weights[t];
        hw_lds[t] = logf(1.f + expf(x)) * 0.13608276f;  // softplus * sqrt(1/54)
    }
    __syncthreads();

    // ---- logits
    const float mq = mask[qn];
    for (int kn = t; kn < NRES; kn += 256) {
        const float mterm = (mq * mask[kn] - 1.f) * 100000.f;
        const float* kp  = kk + kn*192;
        const float* kpt = k_pts + kn*144;
        const float* bp  = bias + ((size_t)qn*NRES + kn)*12;
        #pragma unroll 1
        for (int h = 0; h < 12; ++h) {
            float acc = 0.f;
            #pragma unroll
            for (int c = 0; c < 16; ++c) acc += q_lds[h*16+c] * kp[h*16+c];
            acc *= 0.14433757f;            // sqrt(1/48)
            acc += 0.57735027f * bp[h];    // sqrt(1/3) * bias
            float dsum = 0.f;
            #pragma unroll
            for (int p = 0; p < 4; ++p) {
                int o = (h*4 + p)*3;
                float dx = qp_lds[o]   - kpt[o];
                float dy = qp_lds[o+1] - kpt[o+1];
                float dz = qp_lds[o+2] - kpt[o+2];
                dsum += dx*dx + dy*dy + dz*dz;
            }
            a_lds[h][kn] = acc - 0.5f * hw_lds[h] * dsum + mterm;
        }
    }
    __syncthreads();

    // ---- softmax (exact, per head)
    for (int h = 0; h < 12; ++h) {
        float m = -1e30f;
        for (int kn = t; kn < NRES; kn += 256) m = fmaxf(m, a_lds[h][kn]);
        #pragma unroll
        for (int off = 32; off > 0; off >>= 1) m = fmaxf(m, __shfl_xor(m, off));
        if (lane == 0) red[wv] = m;
        __syncthreads();
        m = fmaxf(fmaxf(red[0], red[1]), fmaxf(red[2], red[3]));
        __syncthreads();
        float ssum = 0.f;
        for (int kn = t; kn < NRES; kn += 256) {
            float e = __expf(a_lds[h][kn] - m);
            a_lds[h][kn] = e;
            ssum += e;
        }
        #pragma unroll
        for (int off = 32; off > 0; off >>= 1) ssum += __shfl_xor(ssum, off);
        if (lane == 0) red[wv] = ssum;
        __syncthreads();
        float inv = 1.f / (red[0] + red[1] + red[2] + red[3]);
        for (int kn = t; kn < NRES; kn += 256) a_lds[h][kn] *= inv;
        __syncthreads();
    }

    // ---- o_pair: second z pass (coalesced float2 per lane), 3 heads per wave
    {
        const int hgrp = t >> 6, c2 = t & 63;
        const int h0 = hgrp*3;
        const float2* zp = (const float2*)(z + (size_t)qn*NRES*CZD) + c2;
        float acc0=0.f,acc1=0.f,acc2=0.f,acc3=0.f,acc4=0.f,acc5=0.f;
        for (int kn = 0; kn < NRES; ++kn) {
            float2 zv = zp[(size_t)kn*64];
            float a0 = a_lds[h0][kn], a1 = a_lds[h0+1][kn], a2 = a_lds[h0+2][kn];
            acc0 += a0*zv.x; acc1 += a0*zv.y;
            acc2 += a1*zv.x; acc3 += a1*zv.y;
            acc4 += a2*zv.x; acc5 += a2*zv.y;
        }
        float* ob = o_cat + qn*2112 + 576;
        ob[(h0+0)*128 + 2*c2] = acc0; ob[(h0+0)*128 + 2*c2 + 1] = acc1;
        ob[(h0+1)*128 + 2*c2] = acc2; ob[(h0+1)*128 + 2*c2 + 1] = acc3;
        ob[(h0+2)*128 + 2*c2] = acc4; ob[(h0+2)*128 + 2*c2 + 1] = acc5;
    }

    // ---- o (192) and o_pt raw (288)
    for (int u = t; u < 480; u += 256) {
        float acc = 0.f;
        if (u < 192) {
            const float* vp = vv + u;
            const float* ap = a_lds[u >> 4];
            for (int kn = 0; kn < NRES; ++kn) acc += ap[kn] * vp[kn*192];
            o_cat[qn*2112 + u] = acc;
        } else {
            int u2 = u - 192;
            const float* vp = v_pts + u2;
            const float* ap = a_lds[u2 / 24];
            for (int kn = 0; kn < NRES; ++kn) acc += ap[kn] * vp[kn*288];
            optraw[u2] = acc;
        }
    }
    __syncthreads();

    // ---- inverse rotation + norms
    if (t < 96) {
        const float* R = rot + qn*9;
        const float* T = trans + qn*3;
        float ox = optraw[t*3]   - T[0];
        float oy = optraw[t*3+1] - T[1];
        float oz = optraw[t*3+2] - T[2];
        float x  = R[0]*ox + R[3]*oy + R[6]*oz;   // R^T (einsum bnji)
        float y  = R[1]*ox + R[4]*oy + R[7]*oz;
        float zc = R[2]*ox + R[5]*oy + R[8]*oz;
        float* ob = o_cat + qn*2112;
        ob[192 + t] = x;
        ob[288 + t] = y;
        ob[384 + t] = zc;
        ob[480 + t] = sqrtf(x*x + y*y + zc*zc + 1e-8f);
    }
}

// ---------------------------------------------------------------- final GEMM (d-chunked, deterministic)
__global__ __launch_bounds__(384) void k_out(
    const float* __restrict__ o_cat, const float* __restrict__ w_out, float* __restrict__ part)
{
    const int dc = blockIdx.x;       // 0..7, 264 d's each
    const int n0 = blockIdx.y * 8;   // n-tile
    const int t = threadIdx.x;       // 384 = output column
    float acc[8];
    #pragma unroll
    for (int nn = 0; nn < 8; ++nn) acc[nn] = 0.f;
    const int d0 = dc * 264;
    for (int d = d0; d < d0 + 264; ++d) {
        float w = w_out[d*384 + t];
        #pragma unroll
        for (int nn = 0; nn < 8; ++nn) acc[nn] += o_cat[(n0+nn)*2112 + d] * w;
    }
    #pragma unroll
    for (int nn = 0; nn < 8; ++nn) part[dc*196608 + (n0+nn)*384 + t] = acc[nn];
}

__global__ __launch_bounds__(256) void k_red(
    const float* __restrict__ part, const float* __restrict__ b_out, float* __restrict__ out)
{
    const int i = blockIdx.x*256 + threadIdx.x;  // < 196608
    float acc = b_out[i % 384];
    #pragma unroll
    for (int dc = 0; dc < 8; ++dc) acc += part[dc*196608 + i];
    out[i] = acc;
}

// ----------------------------------------------------------------
extern "C" void kernel_launch(void* const* d_in, const int* in_sizes, int n_in,
                              void* d_out, int out_size, void* d_ws, size_t ws_size,
                              hipStream_t stream) {
    (void)in_sizes; (void)n_in; (void)out_size; (void)ws_size;
    const float* s      = (const float*)d_in[0];
    const float* z      = (const float*)d_in[1];
    const float* rot    = (const float*)d_in[2];
    const float* trans  = (const float*)d_in[3];
    const float* mask   = (const float*)d_in[4];
    const float* w_q    = (const float*)d_in[5];
    const float* b_q    = (const float*)d_in[6];
    const float* w_kv   = (const float*)d_in[7];
    const float* b_kv   = (const float*)d_in[8];
    const float* w_qp   = (const float*)d_in[9];
    const float* b_qp   = (const float*)d_in[10];
    const float* w_kvp  = (const float*)d_in[11];
    const float* b_kvp  = (const float*)d_in[12];
    const float* w_b    = (const float*)d_in[13];
    const float* b_b    = (const float*)d_in[14];
    const float* hwts   = (const float*)d_in[15];
    const float* w_out  = (const float*)d_in[16];
    const float* b_out  = (const float*)d_in[17];
    float* out = (float*)d_out;
    float* ws  = (float*)d_ws;

    float* q    = ws + OFF_Q;
    float* kk   = ws + OFF_K;
    float* vv   = ws + OFF_V;
    float* qp   = ws + OFF_QP;
    float* kp   = ws + OFF_KP;
    float* vp   = ws + OFF_VP;
    float* bias = ws + OFF_BIAS;
    float* ocat = ws + OFF_OCAT;
    float* part = ws + OFF_PART;
    // praw_* alias the `part` region (disjoint lifetime: consumed by k_rot before k_out writes part)
    float* praw_q  = ws + OFF_PART;
    float* praw_kv = ws + OFF_PART + 73728;

    k_proj<<<dim3(19, 8), dim3(256), 0, stream>>>(s,
        w_q, b_q, w_kv, b_kv, w_qp, b_qp, w_kvp, b_kvp, q, kk, vv, praw_q, praw_kv);
    k_rot<<<dim3(384), dim3(256), 0, stream>>>(praw_q, praw_kv, rot, trans, qp, kp, vp);
    k_bias<<<dim3(8, NRES), dim3(256), 0, stream>>>(z, w_b, b_b, bias);
    k_attn<<<dim3(NRES), dim3(256), 0, stream>>>(z, q, kk, vv, qp, kp, vp,
        bias, hwts, mask, rot, trans, ocat);
    k_out<<<dim3(8, 64), dim3(384), 0, stream>>>(ocat, w_out, part);
    k_red<<<dim3(768), dim3(256), 0, stream>>>(part, b_out, out);
}

// Round 3
// 289.723 us; speedup vs baseline: 3.1744x; 1.7718x over previous
//
#include <hip/hip_runtime.h>
#include <math.h>

#define NRES 512
#define CSD  384
#define CZD  128

// workspace layout (float offsets)
#define OFF_Q     0         //  512*192
#define OFF_KT    98304     //  192*512   kkT[c][k]
#define OFF_VC    196608    //  512*512   vcomb[k][u]  (u<192: v, 192..479: v_pts)
#define OFF_QP    458752    //  512*144   q_pts row-major
#define OFF_KPT   532480    //  144*512   kptsT[dim][k]
#define OFF_A     606208    //  12*512*512  biasT then a (in-place)
#define OFF_OCAT  3751936   //  512*2112
// aliases inside OFF_A region (disjoint lifetimes):
#define OFF_PRAWQ OFF_A            // 512*144 (k_proj -> k_rot)
#define OFF_PRAWK (OFF_A + 73728)  // 512*432
#define OFF_PART  OFF_A            // 8*196608 (k_out -> k_red)

// ---------------------------------------------------------------- projections GEMM
__global__ __launch_bounds__(256) void k_proj(
    const float* __restrict__ s,
    const float* __restrict__ w_q, const float* __restrict__ b_q,
    const float* __restrict__ w_kv, const float* __restrict__ b_kv,
    const float* __restrict__ w_qp, const float* __restrict__ b_qp,
    const float* __restrict__ w_kvp, const float* __restrict__ b_kvp,
    float* __restrict__ q, float* __restrict__ kkT, float* __restrict__ vcomb,
    float* __restrict__ praw_q, float* __restrict__ praw_kv)
{
    const int ct = blockIdx.x;
    const int n0 = blockIdx.y * 64;
    const int t = threadIdx.x;

    const float *w, *bias_p; int od, base, kind;
    if (ct < 3)       { kind=0; w=w_q;   bias_p=b_q;   od=192; base=ct*64; }
    else if (ct < 9)  { kind=1; w=w_kv;  bias_p=b_kv;  od=384; base=(ct-3)*64; }
    else if (ct < 12) { kind=2; w=w_qp;  bias_p=b_qp;  od=144; base=(ct-9)*64; }
    else              { kind=3; w=w_kvp; bias_p=b_kvp; od=432; base=(ct-12)*64; }
    const int valid = min(64, od - base);

    __shared__ float s_lds[64][33];
    __shared__ float w_lds[32][68];

    const int tr = t >> 4, tc = t & 15;
    const int r0 = tr * 4, c0 = tc * 4;
    float acc[4][4];
    #pragma unroll
    for (int i = 0; i < 4; ++i)
        #pragma unroll
        for (int j = 0; j < 4; ++j) acc[i][j] = 0.f;

    for (int k0 = 0; k0 < CSD; k0 += 32) {
        __syncthreads();
        #pragma unroll
        for (int idx = t; idx < 2048; idx += 256) {
            int r = idx >> 5, kx = idx & 31;
            s_lds[r][kx] = s[(n0 + r) * CSD + k0 + kx];
        }
        #pragma unroll
        for (int idx = t; idx < 2048; idx += 256) {
            int kx = idx >> 6, c = idx & 63;
            w_lds[kx][c] = (c < valid) ? w[(k0 + kx) * od + base + c] : 0.f;
        }
        __syncthreads();
        #pragma unroll
        for (int kx = 0; kx < 32; ++kx) {
            float4 bv = *(const float4*)&w_lds[kx][c0];
            float a0 = s_lds[r0+0][kx], a1 = s_lds[r0+1][kx];
            float a2 = s_lds[r0+2][kx], a3 = s_lds[r0+3][kx];
            acc[0][0] += a0*bv.x; acc[0][1] += a0*bv.y; acc[0][2] += a0*bv.z; acc[0][3] += a0*bv.w;
            acc[1][0] += a1*bv.x; acc[1][1] += a1*bv.y; acc[1][2] += a1*bv.z; acc[1][3] += a1*bv.w;
            acc[2][0] += a2*bv.x; acc[2][1] += a2*bv.y; acc[2][2] += a2*bv.z; acc[2][3] += a2*bv.w;
            acc[3][0] += a3*bv.x; acc[3][1] += a3*bv.y; acc[3][2] += a3*bv.z; acc[3][3] += a3*bv.w;
        }
    }

    #pragma unroll
    for (int i = 0; i < 4; ++i) {
        const int n = n0 + r0 + i;
        #pragma unroll
        for (int j = 0; j < 4; ++j) {
            const int c = c0 + j;
            if (c >= valid) continue;
            const int gcol = base + c;
            const float v = acc[i][j] + bias_p[gcol];
            if (kind == 0) {
                q[n*192 + gcol] = v;
            } else if (kind == 1) {
                int h = gcol >> 5, cc = gcol & 31;
                if (cc < 16) kkT[(h*16 + cc)*NRES + n] = v;        // transposed
                else         vcomb[n*NRES + h*16 + (cc-16)] = v;   // k-major, cols 0..191
            } else if (kind == 2) {
                praw_q[n*144 + gcol] = v;
            } else {
                praw_kv[n*432 + gcol] = v;
            }
        }
    }
}

// ---------------------------------------------------------------- rigid-frame rotation
__global__ __launch_bounds__(256) void k_rot(
    const float* __restrict__ praw_q, const float* __restrict__ praw_kv,
    const float* __restrict__ rot, const float* __restrict__ trans,
    float* __restrict__ q_pts, float* __restrict__ kptsT, float* __restrict__ vcomb)
{
    const int idx = blockIdx.x * 256 + threadIdx.x;   // < 512*192
    const int n = idx / 192, u = idx % 192;
    const float* R = rot + n*9;
    const float* T = trans + n*3;
    float px, py, pz;
    if (u < 48) {
        px = praw_q[n*144 + u]; py = praw_q[n*144 + 48 + u]; pz = praw_q[n*144 + 96 + u];
    } else {
        int pt = u - 48;
        px = praw_kv[n*432 + pt]; py = praw_kv[n*432 + 144 + pt]; pz = praw_kv[n*432 + 288 + pt];
    }
    float x  = R[0]*px + R[1]*py + R[2]*pz + T[0];
    float y  = R[3]*px + R[4]*py + R[5]*pz + T[1];
    float zc = R[6]*px + R[7]*py + R[8]*pz + T[2];
    if (u < 48) {
        int o = (n*48 + u)*3;
        q_pts[o] = x; q_pts[o+1] = y; q_pts[o+2] = zc;
    } else {
        int pt = u - 48;
        int h = pt / 12, pp = pt % 12;
        if (pp < 4) {
            int dim = (h*4 + pp)*3;
            kptsT[(dim+0)*NRES + n] = x;
            kptsT[(dim+1)*NRES + n] = y;
            kptsT[(dim+2)*NRES + n] = zc;
        } else {
            int u2 = (h*8 + (pp-4))*3;
            vcomb[n*NRES + 192 + u2+0] = x;
            vcomb[n*NRES + 192 + u2+1] = y;
            vcomb[n*NRES + 192 + u2+2] = zc;
        }
    }
}

// ---------------------------------------------------------------- biasT[h][q][k] = (z @ w_b + b_b)
__global__ __launch_bounds__(256) void k_bias(
    const float* __restrict__ z, const float* __restrict__ w_b, const float* __restrict__ b_b,
    float* __restrict__ biasT)
{
    const int qn = blockIdx.y;
    const int k0 = blockIdx.x * 64;
    const int t = threadIdx.x;
    __shared__ float zt[64*129];
    __shared__ float wb[128*12];
    __shared__ float part[4][64][13];

    for (int i = t; i < 1536; i += 256) wb[i] = w_b[i];
    const float4* zp4 = (const float4*)(z + ((size_t)qn*NRES + k0)*CZD);
    #pragma unroll
    for (int r = 0; r < 8; ++r) {
        int idx = t + r*256;
        int kx = idx >> 5, c4 = idx & 31;
        float4 v4 = zp4[idx];
        float* dst = &zt[kx*129 + c4*4];
        dst[0] = v4.x; dst[1] = v4.y; dst[2] = v4.z; dst[3] = v4.w;
    }
    __syncthreads();

    const int kx = t & 63, qr = t >> 6;
    float acc[12];
    #pragma unroll
    for (int h = 0; h < 12; ++h) acc[h] = 0.f;
    const float* zrow = &zt[kx*129 + qr*32];
    const float* wbp = &wb[qr*32*12];
    for (int c = 0; c < 32; ++c) {
        float zv = zrow[c];
        #pragma unroll
        for (int h = 0; h < 12; ++h) acc[h] += zv * wbp[c*12 + h];
    }
    #pragma unroll
    for (int h = 0; h < 12; ++h) part[qr][kx][h] = acc[h];
    __syncthreads();

    for (int d = t; d < 768; d += 256) {
        int h = d >> 6, k2 = d & 63;
        float b = b_b[h] + part[0][k2][h] + part[1][k2][h] + part[2][k2][h] + part[3][k2][h];
        biasT[(size_t)h*NRES*NRES + (size_t)qn*NRES + k0 + k2] = b;
    }
}

// ---------------------------------------------------------------- logits + softmax, one block per (q,h)
__global__ __launch_bounds__(256) void k_logits(
    const float* __restrict__ q, const float* __restrict__ kkT,
    const float* __restrict__ q_pts, const float* __restrict__ kptsT,
    const float* __restrict__ head_weights, const float* __restrict__ mask,
    float* __restrict__ aT)   // in: biasT, out: softmax'd a (in-place)
{
    const int qn = blockIdx.x, h = blockIdx.y;
    const int t = threadIdx.x;
    const int lane = t & 63, wv = t >> 6;
    __shared__ float red[4];

    const float hw = logf(1.f + expf(head_weights[h])) * 0.13608276f;
    const float mq = mask[qn];
    float qv[16], qpv[12];
    #pragma unroll
    for (int c = 0; c < 16; ++c) qv[c] = q[qn*192 + h*16 + c];
    #pragma unroll
    for (int d = 0; d < 12; ++d) qpv[d] = q_pts[qn*144 + h*12 + d];

    float* arow = aT + (size_t)h*NRES*NRES + (size_t)qn*NRES;
    const float* kT  = kkT + h*16*NRES;
    const float* kpT = kptsT + h*12*NRES;

    float l[2];
    #pragma unroll
    for (int r = 0; r < 2; ++r) {
        const int kn = t + r*256;
        float acc = 0.f;
        #pragma unroll
        for (int c = 0; c < 16; ++c) acc += qv[c] * kT[c*NRES + kn];
        acc *= 0.14433757f;
        acc += 0.57735027f * arow[kn];
        float dsum = 0.f;
        #pragma unroll
        for (int d = 0; d < 12; ++d) {
            float df = qpv[d] - kpT[d*NRES + kn];
            dsum += df*df;
        }
        l[r] = acc - 0.5f * hw * dsum + (mq * mask[kn] - 1.f) * 100000.f;
    }

    // max
    float m = fmaxf(l[0], l[1]);
    #pragma unroll
    for (int off = 32; off > 0; off >>= 1) m = fmaxf(m, __shfl_xor(m, off));
    if (lane == 0) red[wv] = m;
    __syncthreads();
    m = fmaxf(fmaxf(red[0], red[1]), fmaxf(red[2], red[3]));
    __syncthreads();
    // sum
    float e0 = __expf(l[0] - m), e1 = __expf(l[1] - m);
    float ss = e0 + e1;
    #pragma unroll
    for (int off = 32; off > 0; off >>= 1) ss += __shfl_xor(ss, off);
    if (lane == 0) red[wv] = ss;
    __syncthreads();
    const float inv = 1.f / (red[0] + red[1] + red[2] + red[3]);
    arow[t]       = e0 * inv;
    arow[t + 256] = e1 * inv;
}

// ---------------------------------------------------------------- o_pair = a @ z-row
__global__ __launch_bounds__(256) void k_pair(
    const float* __restrict__ aT, const float* __restrict__ z, float* __restrict__ o_cat)
{
    const int qn = blockIdx.x;
    const int t = threadIdx.x;
    __shared__ float a_lds[12][521];
    __shared__ float part[4][12][128];

    for (int i = t; i < 12*NRES; i += 256)
        a_lds[i >> 9][i & 511] = aT[(size_t)(i >> 9)*NRES*NRES + (size_t)qn*NRES + (i & 511)];
    __syncthreads();

    const int c4 = t & 31, kgrp = t >> 5;   // 8 k-groups
    const float4* zp = (const float4*)(z + (size_t)qn*NRES*CZD) + c4;
    float4 acc4[12];
    #pragma unroll
    for (int h = 0; h < 12; ++h) acc4[h] = make_float4(0.f,0.f,0.f,0.f);

    #pragma unroll 4
    for (int kn = kgrp; kn < NRES; kn += 8) {
        float4 zv = zp[kn*32];
        #pragma unroll
        for (int h = 0; h < 12; ++h) {
            float av = a_lds[h][kn];
            acc4[h].x += av*zv.x; acc4[h].y += av*zv.y;
            acc4[h].z += av*zv.z; acc4[h].w += av*zv.w;
        }
    }
    // combine kgrp pairs (lanes l and l^32 hold kgrp 2w, 2w+1 with same c4)
    #pragma unroll
    for (int h = 0; h < 12; ++h) {
        acc4[h].x += __shfl_xor(acc4[h].x, 32);
        acc4[h].y += __shfl_xor(acc4[h].y, 32);
        acc4[h].z += __shfl_xor(acc4[h].z, 32);
        acc4[h].w += __shfl_xor(acc4[h].w, 32);
    }
    const int wave = t >> 6;
    if ((t & 63) < 32) {
        #pragma unroll
        for (int h = 0; h < 12; ++h) {
            part[wave][h][c4*4+0] = acc4[h].x;
            part[wave][h][c4*4+1] = acc4[h].y;
            part[wave][h][c4*4+2] = acc4[h].z;
            part[wave][h][c4*4+3] = acc4[h].w;
        }
    }
    __syncthreads();
    for (int i = t; i < 1536; i += 256) {
        int h = i >> 7, c = i & 127;
        float v = part[0][h][c] + part[1][h][c] + part[2][h][c] + part[3][h][c];
        o_cat[qn*2112 + 576 + h*128 + c] = v;
    }
}

// ---------------------------------------------------------------- o + o_pt + rotation + norms
__global__ __launch_bounds__(512) void k_epi(
    const float* __restrict__ aT, const float* __restrict__ vcomb,
    const float* __restrict__ rot, const float* __restrict__ trans,
    float* __restrict__ o_cat)
{
    const int qn = blockIdx.x;
    const int t = threadIdx.x;
    __shared__ float a_lds[12][521];
    __shared__ float optraw[288];

    for (int i = t; i < 12*NRES; i += 512)
        a_lds[i >> 9][i & 511] = aT[(size_t)(i >> 9)*NRES*NRES + (size_t)qn*NRES + (i & 511)];
    __syncthreads();

    const int h = (t < 192) ? (t >> 4) : ((t < 480) ? (t - 192) / 24 : 0);
    const float* vp = vcomb + t;
    float acc = 0.f;
    #pragma unroll 8
    for (int kn = 0; kn < NRES; ++kn)
        acc += a_lds[h][kn] * vp[(size_t)kn*NRES];

    if (t < 192)            o_cat[qn*2112 + t] = acc;
    else if (t < 480)       optraw[t - 192] = acc;
    __syncthreads();

    if (t < 96) {
        const float* R = rot + qn*9;
        const float* T = trans + qn*3;
        float ox = optraw[t*3]   - T[0];
        float oy = optraw[t*3+1] - T[1];
        float oz = optraw[t*3+2] - T[2];
        float x  = R[0]*ox + R[3]*oy + R[6]*oz;
        float y  = R[1]*ox + R[4]*oy + R[7]*oz;
        float zc = R[2]*ox + R[5]*oy + R[8]*oz;
        float* ob = o_cat + qn*2112;
        ob[192 + t] = x;
        ob[288 + t] = y;
        ob[384 + t] = zc;
        ob[480 + t] = sqrtf(x*x + y*y + zc*zc + 1e-8f);
    }
}

// ---------------------------------------------------------------- final GEMM
__global__ __launch_bounds__(384) void k_out(
    const float* __restrict__ o_cat, const float* __restrict__ w_out, float* __restrict__ part)
{
    const int dc = blockIdx.x;
    const int n0 = blockIdx.y * 8;
    const int t = threadIdx.x;
    float acc[8];
    #pragma unroll
    for (int nn = 0; nn < 8; ++nn) acc[nn] = 0.f;
    const int d0 = dc * 264;
    for (int d = d0; d < d0 + 264; ++d) {
        float w = w_out[d*384 + t];
        #pragma unroll
        for (int nn = 0; nn < 8; ++nn) acc[nn] += o_cat[(n0+nn)*2112 + d] * w;
    }
    #pragma unroll
    for (int nn = 0; nn < 8; ++nn) part[dc*196608 + (n0+nn)*384 + t] = acc[nn];
}

__global__ __launch_bounds__(256) void k_red(
    const float* __restrict__ part, const float* __restrict__ b_out, float* __restrict__ out)
{
    const int i = blockIdx.x*256 + threadIdx.x;
    float acc = b_out[i % 384];
    #pragma unroll
    for (int dc = 0; dc < 8; ++dc) acc += part[dc*196608 + i];
    out[i] = acc;
}

// ----------------------------------------------------------------
extern "C" void kernel_launch(void* const* d_in, const int* in_sizes, int n_in,
                              void* d_out, int out_size, void* d_ws, size_t ws_size,
                              hipStream_t stream) {
    (void)in_sizes; (void)n_in; (void)out_size; (void)ws_size;
    const float* s      = (const float*)d_in[0];
    const float* z      = (const float*)d_in[1];
    const float* rot    = (const float*)d_in[2];
    const float* trans  = (const float*)d_in[3];
    const float* mask   = (const float*)d_in[4];
    const float* w_q    = (const float*)d_in[5];
    const float* b_q    = (const float*)d_in[6];
    const float* w_kv   = (const float*)d_in[7];
    const float* b_kv   = (const float*)d_in[8];
    const float* w_qp   = (const float*)d_in[9];
    const float* b_qp   = (const float*)d_in[10];
    const float* w_kvp  = (const float*)d_in[11];
    const float* b_kvp  = (const float*)d_in[12];
    const float* w_b    = (const float*)d_in[13];
    const float* b_b    = (const float*)d_in[14];
    const float* hwts   = (const float*)d_in[15];
    const float* w_out  = (const float*)d_in[16];
    const float* b_out  = (const float*)d_in[17];
    float* out = (float*)d_out;
    float* ws  = (float*)d_ws;

    float* q      = ws + OFF_Q;
    float* kkT    = ws + OFF_KT;
    float* vcomb  = ws + OFF_VC;
    float* qp     = ws + OFF_QP;
    float* kptsT  = ws + OFF_KPT;
    float* aT     = ws + OFF_A;
    float* ocat   = ws + OFF_OCAT;
    float* part   = ws + OFF_PART;
    float* praw_q  = ws + OFF_PRAWQ;
    float* praw_kv = ws + OFF_PRAWK;

    k_proj<<<dim3(19, 8), dim3(256), 0, stream>>>(s,
        w_q, b_q, w_kv, b_kv, w_qp, b_qp, w_kvp, b_kvp, q, kkT, vcomb, praw_q, praw_kv);
    k_rot<<<dim3(384), dim3(256), 0, stream>>>(praw_q, praw_kv, rot, trans, qp, kptsT, vcomb);
    k_bias<<<dim3(8, NRES), dim3(256), 0, stream>>>(z, w_b, b_b, aT);
    k_logits<<<dim3(NRES, 12), dim3(256), 0, stream>>>(q, kkT, qp, kptsT, hwts, mask, aT);
    k_pair<<<dim3(NRES), dim3(256), 0, stream>>>(aT, z, ocat);
    k_epi<<<dim3(NRES), dim3(512), 0, stream>>>(aT, vcomb, rot, trans, ocat);
    k_out<<<dim3(8, 64), dim3(384), 0, stream>>>(ocat, w_out, part);
    k_red<<<dim3(768), dim3(256), 0, stream>>>(part, b_out, out);
}

// Round 4
// 219.238 us; speedup vs baseline: 4.1950x; 1.3215x over previous
//
#include <hip/hip_runtime.h>
#include <math.h>

#define NRES 512
#define CSD  384
#define CZD  128

// workspace layout (float offsets)
#define OFF_Q     0         //  512*192
#define OFF_KT    98304     //  192*512   kkT[c][k]
#define OFF_VC    196608    //  512*512   vcomb[k][u]  (u<192: v, 192..479: v_pts)
#define OFF_QP    458752    //  512*144   q_pts row-major
#define OFF_KPT   532480    //  144*512   kptsT[dim][k]
#define OFF_A     606208    //  12*512*512  biasT then a (in-place)
#define OFF_OCAT  3751936   //  512*2112
// aliases inside OFF_A region (disjoint lifetimes):
#define OFF_PRAWQ OFF_A            // 512*144 (k_proj -> k_rot)
#define OFF_PRAWK (OFF_A + 73728)  // 512*432
#define OFF_PART  OFF_A            // 6*196608 (k_out -> k_red)

// ---------------------------------------------------------------- projections GEMM
__global__ __launch_bounds__(256) void k_proj(
    const float* __restrict__ s,
    const float* __restrict__ w_q, const float* __restrict__ b_q,
    const float* __restrict__ w_kv, const float* __restrict__ b_kv,
    const float* __restrict__ w_qp, const float* __restrict__ b_qp,
    const float* __restrict__ w_kvp, const float* __restrict__ b_kvp,
    float* __restrict__ q, float* __restrict__ kkT, float* __restrict__ vcomb,
    float* __restrict__ praw_q, float* __restrict__ praw_kv)
{
    const int ct = blockIdx.x;
    const int n0 = blockIdx.y * 64;
    const int t = threadIdx.x;

    const float *w, *bias_p; int od, base, kind;
    if (ct < 3)       { kind=0; w=w_q;   bias_p=b_q;   od=192; base=ct*64; }
    else if (ct < 9)  { kind=1; w=w_kv;  bias_p=b_kv;  od=384; base=(ct-3)*64; }
    else if (ct < 12) { kind=2; w=w_qp;  bias_p=b_qp;  od=144; base=(ct-9)*64; }
    else              { kind=3; w=w_kvp; bias_p=b_kvp; od=432; base=(ct-12)*64; }
    const int valid = min(64, od - base);

    __shared__ float s_lds[64][33];
    __shared__ float w_lds[32][68];

    const int tr = t >> 4, tc = t & 15;
    const int r0 = tr * 4, c0 = tc * 4;
    float acc[4][4];
    #pragma unroll
    for (int i = 0; i < 4; ++i)
        #pragma unroll
        for (int j = 0; j < 4; ++j) acc[i][j] = 0.f;

    for (int k0 = 0; k0 < CSD; k0 += 32) {
        __syncthreads();
        #pragma unroll
        for (int idx = t; idx < 2048; idx += 256) {
            int r = idx >> 5, kx = idx & 31;
            s_lds[r][kx] = s[(n0 + r) * CSD + k0 + kx];
        }
        #pragma unroll
        for (int idx = t; idx < 2048; idx += 256) {
            int kx = idx >> 6, c = idx & 63;
            w_lds[kx][c] = (c < valid) ? w[(k0 + kx) * od + base + c] : 0.f;
        }
        __syncthreads();
        #pragma unroll
        for (int kx = 0; kx < 32; ++kx) {
            float4 bv = *(const float4*)&w_lds[kx][c0];
            float a0 = s_lds[r0+0][kx], a1 = s_lds[r0+1][kx];
            float a2 = s_lds[r0+2][kx], a3 = s_lds[r0+3][kx];
            acc[0][0] += a0*bv.x; acc[0][1] += a0*bv.y; acc[0][2] += a0*bv.z; acc[0][3] += a0*bv.w;
            acc[1][0] += a1*bv.x; acc[1][1] += a1*bv.y; acc[1][2] += a1*bv.z; acc[1][3] += a1*bv.w;
            acc[2][0] += a2*bv.x; acc[2][1] += a2*bv.y; acc[2][2] += a2*bv.z; acc[2][3] += a2*bv.w;
            acc[3][0] += a3*bv.x; acc[3][1] += a3*bv.y; acc[3][2] += a3*bv.z; acc[3][3] += a3*bv.w;
        }
    }

    #pragma unroll
    for (int i = 0; i < 4; ++i) {
        const int n = n0 + r0 + i;
        #pragma unroll
        for (int j = 0; j < 4; ++j) {
            const int c = c0 + j;
            if (c >= valid) continue;
            const int gcol = base + c;
            const float v = acc[i][j] + bias_p[gcol];
            if (kind == 0) {
                q[n*192 + gcol] = v;
            } else if (kind == 1) {
                int h = gcol >> 5, cc = gcol & 31;
                if (cc < 16) kkT[(h*16 + cc)*NRES + n] = v;        // transposed
                else         vcomb[n*NRES + h*16 + (cc-16)] = v;   // k-major, cols 0..191
            } else if (kind == 2) {
                praw_q[n*144 + gcol] = v;
            } else {
                praw_kv[n*432 + gcol] = v;
            }
        }
    }
}

// ---------------------------------------------------------------- rigid-frame rotation
__global__ __launch_bounds__(256) void k_rot(
    const float* __restrict__ praw_q, const float* __restrict__ praw_kv,
    const float* __restrict__ rot, const float* __restrict__ trans,
    float* __restrict__ q_pts, float* __restrict__ kptsT, float* __restrict__ vcomb)
{
    const int idx = blockIdx.x * 256 + threadIdx.x;   // < 512*192
    const int n = idx / 192, u = idx % 192;
    const float* R = rot + n*9;
    const float* T = trans + n*3;
    float px, py, pz;
    if (u < 48) {
        px = praw_q[n*144 + u]; py = praw_q[n*144 + 48 + u]; pz = praw_q[n*144 + 96 + u];
    } else {
        int pt = u - 48;
        px = praw_kv[n*432 + pt]; py = praw_kv[n*432 + 144 + pt]; pz = praw_kv[n*432 + 288 + pt];
    }
    float x  = R[0]*px + R[1]*py + R[2]*pz + T[0];
    float y  = R[3]*px + R[4]*py + R[5]*pz + T[1];
    float zc = R[6]*px + R[7]*py + R[8]*pz + T[2];
    if (u < 48) {
        int o = (n*48 + u)*3;
        q_pts[o] = x; q_pts[o+1] = y; q_pts[o+2] = zc;
    } else {
        int pt = u - 48;
        int h = pt / 12, pp = pt % 12;
        if (pp < 4) {
            int dim = (h*4 + pp)*3;
            kptsT[(dim+0)*NRES + n] = x;
            kptsT[(dim+1)*NRES + n] = y;
            kptsT[(dim+2)*NRES + n] = zc;
        } else {
            int u2 = (h*8 + (pp-4))*3;
            vcomb[n*NRES + 192 + u2+0] = x;
            vcomb[n*NRES + 192 + u2+1] = y;
            vcomb[n*NRES + 192 + u2+2] = zc;
        }
    }
}

// ---------------------------------------------------------------- biasT[h][q][k] = (z @ w_b + b_b)
__global__ __launch_bounds__(256) void k_bias(
    const float* __restrict__ z, const float* __restrict__ w_b, const float* __restrict__ b_b,
    float* __restrict__ biasT)
{
    const int qn = blockIdx.y;
    const int k0 = blockIdx.x * 64;
    const int t = threadIdx.x;
    __shared__ float zt[64*129];
    __shared__ float wb[128*12];
    __shared__ float part[4][64][13];

    for (int i = t; i < 1536; i += 256) wb[i] = w_b[i];
    const float4* zp4 = (const float4*)(z + ((size_t)qn*NRES + k0)*CZD);
    #pragma unroll
    for (int r = 0; r < 8; ++r) {
        int idx = t + r*256;
        int kx = idx >> 5, c4 = idx & 31;
        float4 v4 = zp4[idx];
        float* dst = &zt[kx*129 + c4*4];
        dst[0] = v4.x; dst[1] = v4.y; dst[2] = v4.z; dst[3] = v4.w;
    }
    __syncthreads();

    const int kx = t & 63, qr = t >> 6;
    float acc[12];
    #pragma unroll
    for (int h = 0; h < 12; ++h) acc[h] = 0.f;
    const float* zrow = &zt[kx*129 + qr*32];
    const float* wbp = &wb[qr*32*12];
    for (int c = 0; c < 32; ++c) {
        float zv = zrow[c];
        #pragma unroll
        for (int h = 0; h < 12; ++h) acc[h] += zv * wbp[c*12 + h];
    }
    #pragma unroll
    for (int h = 0; h < 12; ++h) part[qr][kx][h] = acc[h];
    __syncthreads();

    for (int d = t; d < 768; d += 256) {
        int h = d >> 6, k2 = d & 63;
        float b = b_b[h] + part[0][k2][h] + part[1][k2][h] + part[2][k2][h] + part[3][k2][h];
        biasT[(size_t)h*NRES*NRES + (size_t)qn*NRES + k0 + k2] = b;
    }
}

// ---------------------------------------------------------------- logits + softmax, one block per (q,h)
__global__ __launch_bounds__(256) void k_logits(
    const float* __restrict__ q, const float* __restrict__ kkT,
    const float* __restrict__ q_pts, const float* __restrict__ kptsT,
    const float* __restrict__ head_weights, const float* __restrict__ mask,
    float* __restrict__ aT)   // in: biasT, out: softmax'd a (in-place)
{
    const int qn = blockIdx.x, h = blockIdx.y;
    const int t = threadIdx.x;
    const int lane = t & 63, wv = t >> 6;
    __shared__ float red[4];

    const float hw = logf(1.f + expf(head_weights[h])) * 0.13608276f;
    const float mq = mask[qn];
    float qv[16], qpv[12];
    #pragma unroll
    for (int c = 0; c < 16; ++c) qv[c] = q[qn*192 + h*16 + c];
    #pragma unroll
    for (int d = 0; d < 12; ++d) qpv[d] = q_pts[qn*144 + h*12 + d];

    float* arow = aT + (size_t)h*NRES*NRES + (size_t)qn*NRES;
    const float* kT  = kkT + h*16*NRES;
    const float* kpT = kptsT + h*12*NRES;

    float l[2];
    #pragma unroll
    for (int r = 0; r < 2; ++r) {
        const int kn = t + r*256;
        float acc = 0.f;
        #pragma unroll
        for (int c = 0; c < 16; ++c) acc += qv[c] * kT[c*NRES + kn];
        acc *= 0.14433757f;
        acc += 0.57735027f * arow[kn];
        float dsum = 0.f;
        #pragma unroll
        for (int d = 0; d < 12; ++d) {
            float df = qpv[d] - kpT[d*NRES + kn];
            dsum += df*df;
        }
        l[r] = acc - 0.5f * hw * dsum + (mq * mask[kn] - 1.f) * 100000.f;
    }

    // max
    float m = fmaxf(l[0], l[1]);
    #pragma unroll
    for (int off = 32; off > 0; off >>= 1) m = fmaxf(m, __shfl_xor(m, off));
    if (lane == 0) red[wv] = m;
    __syncthreads();
    m = fmaxf(fmaxf(red[0], red[1]), fmaxf(red[2], red[3]));
    __syncthreads();
    // sum
    float e0 = __expf(l[0] - m), e1 = __expf(l[1] - m);
    float ss = e0 + e1;
    #pragma unroll
    for (int off = 32; off > 0; off >>= 1) ss += __shfl_xor(ss, off);
    if (lane == 0) red[wv] = ss;
    __syncthreads();
    const float inv = 1.f / (red[0] + red[1] + red[2] + red[3]);
    arow[t]       = e0 * inv;
    arow[t + 256] = e1 * inv;
}

// ---------------------------------------------------------------- o_pair = a @ z-row
__global__ __launch_bounds__(256) void k_pair(
    const float* __restrict__ aT, const float* __restrict__ z, float* __restrict__ o_cat)
{
    const int qn = blockIdx.x;
    const int t = threadIdx.x;
    __shared__ float a_lds[12][521];
    __shared__ float part[4][12][128];

    for (int i = t; i < 12*NRES; i += 256)
        a_lds[i >> 9][i & 511] = aT[(size_t)(i >> 9)*NRES*NRES + (size_t)qn*NRES + (i & 511)];
    __syncthreads();

    const int c4 = t & 31, kgrp = t >> 5;   // 8 k-groups
    const float4* zp = (const float4*)(z + (size_t)qn*NRES*CZD) + c4;
    float4 acc4[12];
    #pragma unroll
    for (int h = 0; h < 12; ++h) acc4[h] = make_float4(0.f,0.f,0.f,0.f);

    #pragma unroll 4
    for (int kn = kgrp; kn < NRES; kn += 8) {
        float4 zv = zp[kn*32];
        #pragma unroll
        for (int h = 0; h < 12; ++h) {
            float av = a_lds[h][kn];
            acc4[h].x += av*zv.x; acc4[h].y += av*zv.y;
            acc4[h].z += av*zv.z; acc4[h].w += av*zv.w;
        }
    }
    // combine kgrp pairs (lanes l and l^32 hold kgrp 2w, 2w+1 with same c4)
    #pragma unroll
    for (int h = 0; h < 12; ++h) {
        acc4[h].x += __shfl_xor(acc4[h].x, 32);
        acc4[h].y += __shfl_xor(acc4[h].y, 32);
        acc4[h].z += __shfl_xor(acc4[h].z, 32);
        acc4[h].w += __shfl_xor(acc4[h].w, 32);
    }
    const int wave = t >> 6;
    if ((t & 63) < 32) {
        #pragma unroll
        for (int h = 0; h < 12; ++h) {
            part[wave][h][c4*4+0] = acc4[h].x;
            part[wave][h][c4*4+1] = acc4[h].y;
            part[wave][h][c4*4+2] = acc4[h].z;
            part[wave][h][c4*4+3] = acc4[h].w;
        }
    }
    __syncthreads();
    for (int i = t; i < 1536; i += 256) {
        int h = i >> 7, c = i & 127;
        float v = part[0][h][c] + part[1][h][c] + part[2][h][c] + part[3][h][c];
        o_cat[qn*2112 + 576 + h*128 + c] = v;
    }
}

// ---------------------------------------------------------------- o + o_pt + rotation + norms
__global__ __launch_bounds__(512) void k_epi(
    const float* __restrict__ aT, const float* __restrict__ vcomb,
    const float* __restrict__ rot, const float* __restrict__ trans,
    float* __restrict__ o_cat)
{
    const int qn = blockIdx.x;
    const int t = threadIdx.x;
    __shared__ float a_lds[12][521];
    __shared__ float optraw[288];

    for (int i = t; i < 12*NRES; i += 512)
        a_lds[i >> 9][i & 511] = aT[(size_t)(i >> 9)*NRES*NRES + (size_t)qn*NRES + (i & 511)];
    __syncthreads();

    const int h = (t < 192) ? (t >> 4) : ((t < 480) ? (t - 192) / 24 : 0);
    const float* vp = vcomb + t;
    float acc = 0.f;
    #pragma unroll 8
    for (int kn = 0; kn < NRES; ++kn)
        acc += a_lds[h][kn] * vp[(size_t)kn*NRES];

    if (t < 192)            o_cat[qn*2112 + t] = acc;
    else if (t < 480)       optraw[t - 192] = acc;
    __syncthreads();

    if (t < 96) {
        const float* R = rot + qn*9;
        const float* T = trans + qn*3;
        float ox = optraw[t*3]   - T[0];
        float oy = optraw[t*3+1] - T[1];
        float oz = optraw[t*3+2] - T[2];
        float x  = R[0]*ox + R[3]*oy + R[6]*oz;
        float y  = R[1]*ox + R[4]*oy + R[7]*oz;
        float zc = R[2]*ox + R[5]*oy + R[8]*oz;
        float* ob = o_cat + qn*2112;
        ob[192 + t] = x;
        ob[288 + t] = y;
        ob[384 + t] = zc;
        ob[480 + t] = sqrtf(x*x + y*y + zc*zc + 1e-8f);
    }
}

// ---------------------------------------------------------------- final GEMM: 64x64 tiles, K-chunked
// grid = (6 col-tiles, 8 n-tiles, 6 k-chunks of 352)
__global__ __launch_bounds__(256) void k_out(
    const float* __restrict__ o_cat, const float* __restrict__ w_out, float* __restrict__ part)
{
    const int ct = blockIdx.x;       // col tile: 64 cols
    const int n0 = blockIdx.y * 64;  // row tile
    const int kc = blockIdx.z;       // k-chunk: 352
    const int t = threadIdx.x;

    __shared__ float o_lds[64][33];
    __shared__ float w_lds[32][68];

    const int tr = t >> 4, tc = t & 15;
    const int r0 = tr * 4, c0 = tc * 4;
    float acc[4][4];
    #pragma unroll
    for (int i = 0; i < 4; ++i)
        #pragma unroll
        for (int j = 0; j < 4; ++j) acc[i][j] = 0.f;

    const int kbase = kc * 352;
    for (int k0 = kbase; k0 < kbase + 352; k0 += 32) {
        __syncthreads();
        #pragma unroll
        for (int idx = t; idx < 2048; idx += 256) {
            int r = idx >> 5, kx = idx & 31;
            o_lds[r][kx] = o_cat[(n0 + r) * 2112 + k0 + kx];
        }
        #pragma unroll
        for (int idx = t; idx < 2048; idx += 256) {
            int kx = idx >> 6, c = idx & 63;
            w_lds[kx][c] = w_out[(k0 + kx) * 384 + ct*64 + c];
        }
        __syncthreads();
        #pragma unroll
        for (int kx = 0; kx < 32; ++kx) {
            float4 bv = *(const float4*)&w_lds[kx][c0];
            float a0 = o_lds[r0+0][kx], a1 = o_lds[r0+1][kx];
            float a2 = o_lds[r0+2][kx], a3 = o_lds[r0+3][kx];
            acc[0][0] += a0*bv.x; acc[0][1] += a0*bv.y; acc[0][2] += a0*bv.z; acc[0][3] += a0*bv.w;
            acc[1][0] += a1*bv.x; acc[1][1] += a1*bv.y; acc[1][2] += a1*bv.z; acc[1][3] += a1*bv.w;
            acc[2][0] += a2*bv.x; acc[2][1] += a2*bv.y; acc[2][2] += a2*bv.z; acc[2][3] += a2*bv.w;
            acc[3][0] += a3*bv.x; acc[3][1] += a3*bv.y; acc[3][2] += a3*bv.z; acc[3][3] += a3*bv.w;
        }
    }

    float* pp = part + (size_t)kc * 196608;
    #pragma unroll
    for (int i = 0; i < 4; ++i) {
        const int n = n0 + r0 + i;
        #pragma unroll
        for (int j = 0; j < 4; ++j)
            pp[n*384 + ct*64 + c0 + j] = acc[i][j];
    }
}

__global__ __launch_bounds__(256) void k_red(
    const float* __restrict__ part, const float* __restrict__ b_out, float* __restrict__ out)
{
    const int i = blockIdx.x*256 + threadIdx.x;
    float acc = b_out[i % 384];
    #pragma unroll
    for (int dc = 0; dc < 6; ++dc) acc += part[(size_t)dc*196608 + i];
    out[i] = acc;
}

// ----------------------------------------------------------------
extern "C" void kernel_launch(void* const* d_in, const int* in_sizes, int n_in,
                              void* d_out, int out_size, void* d_ws, size_t ws_size,
                              hipStream_t stream) {
    (void)in_sizes; (void)n_in; (void)out_size; (void)ws_size;
    const float* s      = (const float*)d_in[0];
    const float* z      = (const float*)d_in[1];
    const float* rot    = (const float*)d_in[2];
    const float* trans  = (const float*)d_in[3];
    const float* mask   = (const float*)d_in[4];
    const float* w_q    = (const float*)d_in[5];
    const float* b_q    = (const float*)d_in[6];
    const float* w_kv   = (const float*)d_in[7];
    const float* b_kv   = (const float*)d_in[8];
    const float* w_qp   = (const float*)d_in[9];
    const float* b_qp   = (const float*)d_in[10];
    const float* w_kvp  = (const float*)d_in[11];
    const float* b_kvp  = (const float*)d_in[12];
    const float* w_b    = (const float*)d_in[13];
    const float* b_b    = (const float*)d_in[14];
    const float* hwts   = (const float*)d_in[15];
    const float* w_out  = (const float*)d_in[16];
    const float* b_out  = (const float*)d_in[17];
    float* out = (float*)d_out;
    float* ws  = (float*)d_ws;

    float* q      = ws + OFF_Q;
    float* kkT    = ws + OFF_KT;
    float* vcomb  = ws + OFF_VC;
    float* qp     = ws + OFF_QP;
    float* kptsT  = ws + OFF_KPT;
    float* aT     = ws + OFF_A;
    float* ocat   = ws + OFF_OCAT;
    float* part   = ws + OFF_PART;
    float* praw_q  = ws + OFF_PRAWQ;
    float* praw_kv = ws + OFF_PRAWK;

    k_proj<<<dim3(19, 8), dim3(256), 0, stream>>>(s,
        w_q, b_q, w_kv, b_kv, w_qp, b_qp, w_kvp, b_kvp, q, kkT, vcomb, praw_q, praw_kv);
    k_rot<<<dim3(384), dim3(256), 0, stream>>>(praw_q, praw_kv, rot, trans, qp, kptsT, vcomb);
    k_bias<<<dim3(8, NRES), dim3(256), 0, stream>>>(z, w_b, b_b, aT);
    k_logits<<<dim3(NRES, 12), dim3(256), 0, stream>>>(q, kkT, qp, kptsT, hwts, mask, aT);
    k_pair<<<dim3(NRES), dim3(256), 0, stream>>>(aT, z, ocat);
    k_epi<<<dim3(NRES), dim3(512), 0, stream>>>(aT, vcomb, rot, trans, ocat);
    k_out<<<dim3(6, 8, 6), dim3(256), 0, stream>>>(ocat, w_out, part);
    k_red<<<dim3(768), dim3(256), 0, stream>>>(part, b_out, out);
}

// Round 5
// 166.742 us; speedup vs baseline: 5.5157x; 1.3148x over previous
//
#include <hip/hip_runtime.h>
#include <math.h>

#define NRES 512
#define CSD  384
#define CZD  128

// workspace layout (float offsets)
#define OFF_Q     0         //  512*192
#define OFF_KT    98304     //  192*512   kkT[c][k]
#define OFF_VC    196608    //  512*512   vcomb[k][u]  (u<192: v, 192..479: v_pts)
#define OFF_QP    458752    //  512*144   q_pts row-major
#define OFF_KPT   532480    //  144*512   kptsT[dim][k]
#define OFF_A     606208    //  12*512*512  biasT then a (in-place)
#define OFF_OCAT  3751936   //  512*2112
#define OFF_WCAT  4833280   //  384*1152 wcat + 1152 bcat
#define OFF_BCAT  (OFF_WCAT + 442368)
// aliases inside OFF_A region (disjoint lifetimes):
#define OFF_PRAWQ OFF_A            // 512*144 (k_proj2 -> k_rot)
#define OFF_PRAWK (OFF_A + 73728)  // 512*432
#define OFF_PART  OFF_A            // 6*196608 (k_out2 -> k_red)

// ---------------------------------------------------------------- weight concat
__global__ __launch_bounds__(256) void k_wcat(
    const float* __restrict__ w_q, const float* __restrict__ b_q,
    const float* __restrict__ w_kv, const float* __restrict__ b_kv,
    const float* __restrict__ w_qp, const float* __restrict__ b_qp,
    const float* __restrict__ w_kvp, const float* __restrict__ b_kvp,
    float* __restrict__ wcat, float* __restrict__ bcat)
{
    const int idx = blockIdx.x * 256 + threadIdx.x;
    if (idx < 442368) {
        const int k = idx / 1152, c = idx % 1152;
        float v;
        if (c < 192)      v = w_q[k*192 + c];
        else if (c < 576) v = w_kv[k*384 + (c - 192)];
        else if (c < 720) v = w_qp[k*144 + (c - 576)];
        else              v = w_kvp[k*432 + (c - 720)];
        wcat[idx] = v;
    } else if (idx < 443520) {
        const int c = idx - 442368;
        float v;
        if (c < 192)      v = b_q[c];
        else if (c < 576) v = b_kv[c - 192];
        else if (c < 720) v = b_qp[c - 576];
        else              v = b_kvp[c - 720];
        bcat[c] = v;
    }
}

// ---------------------------------------------------------------- projections GEMM, latency-optimized
// 32x32 tiles, 2x2 micro, reg-prefetch pipeline. grid = (36 col-tiles, 16 n-tiles)
__global__ __launch_bounds__(256) void k_proj2(
    const float* __restrict__ s, const float* __restrict__ wcat, const float* __restrict__ bcat,
    float* __restrict__ q, float* __restrict__ kkT, float* __restrict__ vcomb,
    float* __restrict__ praw_q, float* __restrict__ praw_kv)
{
    const int ct = blockIdx.x;          // 36 tiles of 32 cols
    const int n0 = blockIdx.y * 32;
    const int t = threadIdx.x;

    __shared__ float sT[32][34];        // [k][row], pad 34 for b64 align
    __shared__ float wt[32][36];        // [k][col], pad 36 for b64/b128 align

    const int lr = t >> 3, lc4 = t & 7; // staging: row/krow + float4 col
    const int tr = t >> 4, tc = t & 15; // compute: 16x16 threads
    float4 sv4, wv4;

    // prologue: chunk 0
    sv4 = *(const float4*)&s[(n0 + lr) * CSD + lc4 * 4];
    wv4 = *(const float4*)&wcat[lr * 1152 + ct * 32 + lc4 * 4];
    sT[lc4*4+0][lr] = sv4.x; sT[lc4*4+1][lr] = sv4.y; sT[lc4*4+2][lr] = sv4.z; sT[lc4*4+3][lr] = sv4.w;
    *(float4*)&wt[lr][lc4*4] = wv4;
    __syncthreads();

    float a00 = 0.f, a01 = 0.f, a10 = 0.f, a11 = 0.f;

    for (int it = 0; it < 12; ++it) {
        if (it < 11) {
            const int k0 = (it + 1) * 32;
            sv4 = *(const float4*)&s[(n0 + lr) * CSD + k0 + lc4 * 4];
            wv4 = *(const float4*)&wcat[(k0 + lr) * 1152 + ct * 32 + lc4 * 4];
        }
        #pragma unroll
        for (int kx = 0; kx < 32; ++kx) {
            float2 ss = *(const float2*)&sT[kx][tr * 2];
            float2 ww = *(const float2*)&wt[kx][tc * 2];
            a00 += ss.x * ww.x; a01 += ss.x * ww.y;
            a10 += ss.y * ww.x; a11 += ss.y * ww.y;
        }
        __syncthreads();
        if (it < 11) {
            sT[lc4*4+0][lr] = sv4.x; sT[lc4*4+1][lr] = sv4.y; sT[lc4*4+2][lr] = sv4.z; sT[lc4*4+3][lr] = sv4.w;
            *(float4*)&wt[lr][lc4*4] = wv4;
            __syncthreads();
        }
    }

    // epilogue: bias + scatter
    float accv[2][2] = {{a00, a01}, {a10, a11}};
    #pragma unroll
    for (int i = 0; i < 2; ++i) {
        const int n = n0 + tr * 2 + i;
        #pragma unroll
        for (int j = 0; j < 2; ++j) {
            const int gcol = ct * 32 + tc * 2 + j;
            const float v = accv[i][j] + bcat[gcol];
            if (gcol < 192) {
                q[n*192 + gcol] = v;
            } else if (gcol < 576) {
                int g = gcol - 192, h = g >> 5, cc = g & 31;
                if (cc < 16) kkT[(h*16 + cc)*NRES + n] = v;
                else         vcomb[n*NRES + h*16 + (cc-16)] = v;
            } else if (gcol < 720) {
                praw_q[n*144 + (gcol - 576)] = v;
            } else {
                praw_kv[n*432 + (gcol - 720)] = v;
            }
        }
    }
}

// ---------------------------------------------------------------- rigid-frame rotation
__global__ __launch_bounds__(256) void k_rot(
    const float* __restrict__ praw_q, const float* __restrict__ praw_kv,
    const float* __restrict__ rot, const float* __restrict__ trans,
    float* __restrict__ q_pts, float* __restrict__ kptsT, float* __restrict__ vcomb)
{
    const int idx = blockIdx.x * 256 + threadIdx.x;   // < 512*192
    const int n = idx / 192, u = idx % 192;
    const float* R = rot + n*9;
    const float* T = trans + n*3;
    float px, py, pz;
    if (u < 48) {
        px = praw_q[n*144 + u]; py = praw_q[n*144 + 48 + u]; pz = praw_q[n*144 + 96 + u];
    } else {
        int pt = u - 48;
        px = praw_kv[n*432 + pt]; py = praw_kv[n*432 + 144 + pt]; pz = praw_kv[n*432 + 288 + pt];
    }
    float x  = R[0]*px + R[1]*py + R[2]*pz + T[0];
    float y  = R[3]*px + R[4]*py + R[5]*pz + T[1];
    float zc = R[6]*px + R[7]*py + R[8]*pz + T[2];
    if (u < 48) {
        int o = (n*48 + u)*3;
        q_pts[o] = x; q_pts[o+1] = y; q_pts[o+2] = zc;
    } else {
        int pt = u - 48;
        int h = pt / 12, pp = pt % 12;
        if (pp < 4) {
            int dim = (h*4 + pp)*3;
            kptsT[(dim+0)*NRES + n] = x;
            kptsT[(dim+1)*NRES + n] = y;
            kptsT[(dim+2)*NRES + n] = zc;
        } else {
            int u2 = (h*8 + (pp-4))*3;
            vcomb[n*NRES + 192 + u2+0] = x;
            vcomb[n*NRES + 192 + u2+1] = y;
            vcomb[n*NRES + 192 + u2+2] = zc;
        }
    }
}

// ---------------------------------------------------------------- biasT[h][q][k] = (z @ w_b + b_b)
__global__ __launch_bounds__(256) void k_bias(
    const float* __restrict__ z, const float* __restrict__ w_b, const float* __restrict__ b_b,
    float* __restrict__ biasT)
{
    const int qn = blockIdx.y;
    const int k0 = blockIdx.x * 64;
    const int t = threadIdx.x;
    __shared__ float zt[64*129];
    __shared__ float wb[128*12];
    __shared__ float part[4][64][13];

    for (int i = t; i < 1536; i += 256) wb[i] = w_b[i];
    const float4* zp4 = (const float4*)(z + ((size_t)qn*NRES + k0)*CZD);
    #pragma unroll
    for (int r = 0; r < 8; ++r) {
        int idx = t + r*256;
        int kx = idx >> 5, c4 = idx & 31;
        float4 v4 = zp4[idx];
        float* dst = &zt[kx*129 + c4*4];
        dst[0] = v4.x; dst[1] = v4.y; dst[2] = v4.z; dst[3] = v4.w;
    }
    __syncthreads();

    const int kx = t & 63, qr = t >> 6;
    float acc[12];
    #pragma unroll
    for (int h = 0; h < 12; ++h) acc[h] = 0.f;
    const float* zrow = &zt[kx*129 + qr*32];
    const float* wbp = &wb[qr*32*12];
    for (int c = 0; c < 32; ++c) {
        float zv = zrow[c];
        #pragma unroll
        for (int h = 0; h < 12; ++h) acc[h] += zv * wbp[c*12 + h];
    }
    #pragma unroll
    for (int h = 0; h < 12; ++h) part[qr][kx][h] = acc[h];
    __syncthreads();

    for (int d = t; d < 768; d += 256) {
        int h = d >> 6, k2 = d & 63;
        float b = b_b[h] + part[0][k2][h] + part[1][k2][h] + part[2][k2][h] + part[3][k2][h];
        biasT[(size_t)h*NRES*NRES + (size_t)qn*NRES + k0 + k2] = b;
    }
}

// ---------------------------------------------------------------- logits + softmax, one block per (q,h)
__global__ __launch_bounds__(256) void k_logits(
    const float* __restrict__ q, const float* __restrict__ kkT,
    const float* __restrict__ q_pts, const float* __restrict__ kptsT,
    const float* __restrict__ head_weights, const float* __restrict__ mask,
    float* __restrict__ aT)   // in: biasT, out: softmax'd a (in-place)
{
    const int qn = blockIdx.x, h = blockIdx.y;
    const int t = threadIdx.x;
    const int lane = t & 63, wv = t >> 6;
    __shared__ float red[4];

    const float hw = logf(1.f + expf(head_weights[h])) * 0.13608276f;
    const float mq = mask[qn];
    float qv[16], qpv[12];
    #pragma unroll
    for (int c = 0; c < 16; ++c) qv[c] = q[qn*192 + h*16 + c];
    #pragma unroll
    for (int d = 0; d < 12; ++d) qpv[d] = q_pts[qn*144 + h*12 + d];

    float* arow = aT + (size_t)h*NRES*NRES + (size_t)qn*NRES;
    const float* kT  = kkT + h*16*NRES;
    const float* kpT = kptsT + h*12*NRES;

    float l[2];
    #pragma unroll
    for (int r = 0; r < 2; ++r) {
        const int kn = t + r*256;
        float acc = 0.f;
        #pragma unroll
        for (int c = 0; c < 16; ++c) acc += qv[c] * kT[c*NRES + kn];
        acc *= 0.14433757f;
        acc += 0.57735027f * arow[kn];
        float dsum = 0.f;
        #pragma unroll
        for (int d = 0; d < 12; ++d) {
            float df = qpv[d] - kpT[d*NRES + kn];
            dsum += df*df;
        }
        l[r] = acc - 0.5f * hw * dsum + (mq * mask[kn] - 1.f) * 100000.f;
    }

    // max
    float m = fmaxf(l[0], l[1]);
    #pragma unroll
    for (int off = 32; off > 0; off >>= 1) m = fmaxf(m, __shfl_xor(m, off));
    if (lane == 0) red[wv] = m;
    __syncthreads();
    m = fmaxf(fmaxf(red[0], red[1]), fmaxf(red[2], red[3]));
    __syncthreads();
    // sum
    float e0 = __expf(l[0] - m), e1 = __expf(l[1] - m);
    float ss = e0 + e1;
    #pragma unroll
    for (int off = 32; off > 0; off >>= 1) ss += __shfl_xor(ss, off);
    if (lane == 0) red[wv] = ss;
    __syncthreads();
    const float inv = 1.f / (red[0] + red[1] + red[2] + red[3]);
    arow[t]       = e0 * inv;
    arow[t + 256] = e1 * inv;
}

// ---------------------------------------------------------------- o_pair = a @ z-row
__global__ __launch_bounds__(256) void k_pair(
    const float* __restrict__ aT, const float* __restrict__ z, float* __restrict__ o_cat)
{
    const int qn = blockIdx.x;
    const int t = threadIdx.x;
    __shared__ float a_lds[12][521];
    __shared__ float part[4][12][128];

    for (int i = t; i < 12*NRES; i += 256)
        a_lds[i >> 9][i & 511] = aT[(size_t)(i >> 9)*NRES*NRES + (size_t)qn*NRES + (i & 511)];
    __syncthreads();

    const int c4 = t & 31, kgrp = t >> 5;   // 8 k-groups
    const float4* zp = (const float4*)(z + (size_t)qn*NRES*CZD) + c4;
    float4 acc4[12];
    #pragma unroll
    for (int h = 0; h < 12; ++h) acc4[h] = make_float4(0.f,0.f,0.f,0.f);

    #pragma unroll 4
    for (int kn = kgrp; kn < NRES; kn += 8) {
        float4 zv = zp[kn*32];
        #pragma unroll
        for (int h = 0; h < 12; ++h) {
            float av = a_lds[h][kn];
            acc4[h].x += av*zv.x; acc4[h].y += av*zv.y;
            acc4[h].z += av*zv.z; acc4[h].w += av*zv.w;
        }
    }
    #pragma unroll
    for (int h = 0; h < 12; ++h) {
        acc4[h].x += __shfl_xor(acc4[h].x, 32);
        acc4[h].y += __shfl_xor(acc4[h].y, 32);
        acc4[h].z += __shfl_xor(acc4[h].z, 32);
        acc4[h].w += __shfl_xor(acc4[h].w, 32);
    }
    const int wave = t >> 6;
    if ((t & 63) < 32) {
        #pragma unroll
        for (int h = 0; h < 12; ++h) {
            part[wave][h][c4*4+0] = acc4[h].x;
            part[wave][h][c4*4+1] = acc4[h].y;
            part[wave][h][c4*4+2] = acc4[h].z;
            part[wave][h][c4*4+3] = acc4[h].w;
        }
    }
    __syncthreads();
    for (int i = t; i < 1536; i += 256) {
        int h = i >> 7, c = i & 127;
        float v = part[0][h][c] + part[1][h][c] + part[2][h][c] + part[3][h][c];
        o_cat[qn*2112 + 576 + h*128 + c] = v;
    }
}

// ---------------------------------------------------------------- o + o_pt + rotation + norms
__global__ __launch_bounds__(512) void k_epi(
    const float* __restrict__ aT, const float* __restrict__ vcomb,
    const float* __restrict__ rot, const float* __restrict__ trans,
    float* __restrict__ o_cat)
{
    const int qn = blockIdx.x;
    const int t = threadIdx.x;
    __shared__ float a_lds[12][521];
    __shared__ float optraw[288];

    for (int i = t; i < 12*NRES; i += 512)
        a_lds[i >> 9][i & 511] = aT[(size_t)(i >> 9)*NRES*NRES + (size_t)qn*NRES + (i & 511)];
    __syncthreads();

    const int h = (t < 192) ? (t >> 4) : ((t < 480) ? (t - 192) / 24 : 0);
    const float* vp = vcomb + t;
    float acc = 0.f;
    #pragma unroll 8
    for (int kn = 0; kn < NRES; ++kn)
        acc += a_lds[h][kn] * vp[(size_t)kn*NRES];

    if (t < 192)            o_cat[qn*2112 + t] = acc;
    else if (t < 480)       optraw[t - 192] = acc;
    __syncthreads();

    if (t < 96) {
        const float* R = rot + qn*9;
        const float* T = trans + qn*3;
        float ox = optraw[t*3]   - T[0];
        float oy = optraw[t*3+1] - T[1];
        float oz = optraw[t*3+2] - T[2];
        float x  = R[0]*ox + R[3]*oy + R[6]*oz;
        float y  = R[1]*ox + R[4]*oy + R[7]*oz;
        float zc = R[2]*ox + R[5]*oy + R[8]*oz;
        float* ob = o_cat + qn*2112;
        ob[192 + t] = x;
        ob[288 + t] = y;
        ob[384 + t] = zc;
        ob[480 + t] = sqrtf(x*x + y*y + zc*zc + 1e-8f);
    }
}

// ---------------------------------------------------------------- final GEMM, latency-optimized
// 32x32 tiles, 2x2 micro, reg-prefetch. grid = (12 ct, 16 nt, 6 kc of 352)
__global__ __launch_bounds__(256) void k_out2(
    const float* __restrict__ o_cat, const float* __restrict__ w_out, float* __restrict__ part)
{
    const int ct = blockIdx.x;
    const int n0 = blockIdx.y * 32;
    const int kc = blockIdx.z;
    const int t = threadIdx.x;

    __shared__ float oT[32][34];
    __shared__ float wt[32][36];

    const int lr = t >> 3, lc4 = t & 7;
    const int tr = t >> 4, tc = t & 15;
    const int kbase = kc * 352;
    float4 ov4, wv4;

    ov4 = *(const float4*)&o_cat[(n0 + lr) * 2112 + kbase + lc4 * 4];
    wv4 = *(const float4*)&w_out[(kbase + lr) * 384 + ct * 32 + lc4 * 4];
    oT[lc4*4+0][lr] = ov4.x; oT[lc4*4+1][lr] = ov4.y; oT[lc4*4+2][lr] = ov4.z; oT[lc4*4+3][lr] = ov4.w;
    *(float4*)&wt[lr][lc4*4] = wv4;
    __syncthreads();

    float a00 = 0.f, a01 = 0.f, a10 = 0.f, a11 = 0.f;

    for (int it = 0; it < 11; ++it) {
        if (it < 10) {
            const int k0 = kbase + (it + 1) * 32;
            ov4 = *(const float4*)&o_cat[(n0 + lr) * 2112 + k0 + lc4 * 4];
            wv4 = *(const float4*)&w_out[(k0 + lr) * 384 + ct * 32 + lc4 * 4];
        }
        #pragma unroll
        for (int kx = 0; kx < 32; ++kx) {
            float2 oo = *(const float2*)&oT[kx][tr * 2];
            float2 ww = *(const float2*)&wt[kx][tc * 2];
            a00 += oo.x * ww.x; a01 += oo.x * ww.y;
            a10 += oo.y * ww.x; a11 += oo.y * ww.y;
        }
        __syncthreads();
        if (it < 10) {
            oT[lc4*4+0][lr] = ov4.x; oT[lc4*4+1][lr] = ov4.y; oT[lc4*4+2][lr] = ov4.z; oT[lc4*4+3][lr] = ov4.w;
            *(float4*)&wt[lr][lc4*4] = wv4;
            __syncthreads();
        }
    }

    float* pp = part + (size_t)kc * 196608;
    pp[(n0 + tr*2 + 0)*384 + ct*32 + tc*2 + 0] = a00;
    pp[(n0 + tr*2 + 0)*384 + ct*32 + tc*2 + 1] = a01;
    pp[(n0 + tr*2 + 1)*384 + ct*32 + tc*2 + 0] = a10;
    pp[(n0 + tr*2 + 1)*384 + ct*32 + tc*2 + 1] = a11;
}

__global__ __launch_bounds__(256) void k_red(
    const float* __restrict__ part, const float* __restrict__ b_out, float* __restrict__ out)
{
    const int i = blockIdx.x*256 + threadIdx.x;
    float acc = b_out[i % 384];
    #pragma unroll
    for (int dc = 0; dc < 6; ++dc) acc += part[(size_t)dc*196608 + i];
    out[i] = acc;
}

// ----------------------------------------------------------------
extern "C" void kernel_launch(void* const* d_in, const int* in_sizes, int n_in,
                              void* d_out, int out_size, void* d_ws, size_t ws_size,
                              hipStream_t stream) {
    (void)in_sizes; (void)n_in; (void)out_size; (void)ws_size;
    const float* s      = (const float*)d_in[0];
    const float* z      = (const float*)d_in[1];
    const float* rot    = (const float*)d_in[2];
    const float* trans  = (const float*)d_in[3];
    const float* mask   = (const float*)d_in[4];
    const float* w_q    = (const float*)d_in[5];
    const float* b_q    = (const float*)d_in[6];
    const float* w_kv   = (const float*)d_in[7];
    const float* b_kv   = (const float*)d_in[8];
    const float* w_qp   = (const float*)d_in[9];
    const float* b_qp   = (const float*)d_in[10];
    const float* w_kvp  = (const float*)d_in[11];
    const float* b_kvp  = (const float*)d_in[12];
    const float* w_b    = (const float*)d_in[13];
    const float* b_b    = (const float*)d_in[14];
    const float* hwts   = (const float*)d_in[15];
    const float* w_out  = (const float*)d_in[16];
    const float* b_out  = (const float*)d_in[17];
    float* out = (float*)d_out;
    float* ws  = (float*)d_ws;

    float* q      = ws + OFF_Q;
    float* kkT    = ws + OFF_KT;
    float* vcomb  = ws + OFF_VC;
    float* qp     = ws + OFF_QP;
    float* kptsT  = ws + OFF_KPT;
    float* aT     = ws + OFF_A;
    float* ocat   = ws + OFF_OCAT;
    float* wcat   = ws + OFF_WCAT;
    float* bcat   = ws + OFF_BCAT;
    float* part   = ws + OFF_PART;
    float* praw_q  = ws + OFF_PRAWQ;
    float* praw_kv = ws + OFF_PRAWK;

    k_wcat<<<dim3(1733), dim3(256), 0, stream>>>(w_q, b_q, w_kv, b_kv, w_qp, b_qp, w_kvp, b_kvp, wcat, bcat);
    k_proj2<<<dim3(36, 16), dim3(256), 0, stream>>>(s, wcat, bcat, q, kkT, vcomb, praw_q, praw_kv);
    k_rot<<<dim3(384), dim3(256), 0, stream>>>(praw_q, praw_kv, rot, trans, qp, kptsT, vcomb);
    k_bias<<<dim3(8, NRES), dim3(256), 0, stream>>>(z, w_b, b_b, aT);
    k_logits<<<dim3(NRES, 12), dim3(256), 0, stream>>>(q, kkT, qp, kptsT, hwts, mask, aT);
    k_pair<<<dim3(NRES), dim3(256), 0, stream>>>(aT, z, ocat);
    k_epi<<<dim3(NRES), dim3(512), 0, stream>>>(aT, vcomb, rot, trans, ocat);
    k_out2<<<dim3(12, 16, 6), dim3(256), 0, stream>>>(ocat, w_out, part);
    k_red<<<dim3(768), dim3(256), 0, stream>>>(part, b_out, out);
}

// Round 6
// 149.802 us; speedup vs baseline: 6.1395x; 1.1131x over previous
//
#include <hip/hip_runtime.h>
#include <math.h>

#define NRES 512
#define CSD  384
#define CZD  128

// workspace layout (float offsets)
#define OFF_Q     0         //  512*192
#define OFF_KT    98304     //  192*512   kkT[c][k]
#define OFF_VC    196608    //  512*512   vcomb[k][u]  (u<192: v, 192..479: v_pts)
#define OFF_QP    458752    //  512*144   q_pts row-major
#define OFF_KPT   532480    //  144*512   kptsT[dim][k]
#define OFF_A     606208    //  scratch region (praw / part aliases)
#define OFF_OCAT  3751936   //  512*2112
#define OFF_WCAT  4833280   //  384*1152 wcat + 1152 bcat
#define OFF_BCAT  (OFF_WCAT + 442368)
// aliases inside OFF_A region (disjoint lifetimes):
#define OFF_PRAWQ OFF_A            // 512*144 (k_proj2 -> k_rot)
#define OFF_PRAWK (OFF_A + 73728)  // 512*432
#define OFF_PART  OFF_A            // 6*196608 (k_out2 -> k_red)

// ---------------------------------------------------------------- weight concat
__global__ __launch_bounds__(256) void k_wcat(
    const float* __restrict__ w_q, const float* __restrict__ b_q,
    const float* __restrict__ w_kv, const float* __restrict__ b_kv,
    const float* __restrict__ w_qp, const float* __restrict__ b_qp,
    const float* __restrict__ w_kvp, const float* __restrict__ b_kvp,
    float* __restrict__ wcat, float* __restrict__ bcat)
{
    const int idx = blockIdx.x * 256 + threadIdx.x;
    if (idx < 442368) {
        const int k = idx / 1152, c = idx % 1152;
        float v;
        if (c < 192)      v = w_q[k*192 + c];
        else if (c < 576) v = w_kv[k*384 + (c - 192)];
        else if (c < 720) v = w_qp[k*144 + (c - 576)];
        else              v = w_kvp[k*432 + (c - 720)];
        wcat[idx] = v;
    } else if (idx < 443520) {
        const int c = idx - 442368;
        float v;
        if (c < 192)      v = b_q[c];
        else if (c < 576) v = b_kv[c - 192];
        else if (c < 720) v = b_qp[c - 576];
        else              v = b_kvp[c - 720];
        bcat[c] = v;
    }
}

// ---------------------------------------------------------------- projections GEMM
// 32x32 tiles, 2x2 micro, reg-prefetch. grid = (36, 16)
__global__ __launch_bounds__(256) void k_proj2(
    const float* __restrict__ s, const float* __restrict__ wcat, const float* __restrict__ bcat,
    float* __restrict__ q, float* __restrict__ kkT, float* __restrict__ vcomb,
    float* __restrict__ praw_q, float* __restrict__ praw_kv)
{
    const int ct = blockIdx.x;
    const int n0 = blockIdx.y * 32;
    const int t = threadIdx.x;

    __shared__ float sT[32][34];
    __shared__ float wt[32][36];

    const int lr = t >> 3, lc4 = t & 7;
    const int tr = t >> 4, tc = t & 15;
    float4 sv4, wv4;

    sv4 = *(const float4*)&s[(n0 + lr) * CSD + lc4 * 4];
    wv4 = *(const float4*)&wcat[lr * 1152 + ct * 32 + lc4 * 4];
    sT[lc4*4+0][lr] = sv4.x; sT[lc4*4+1][lr] = sv4.y; sT[lc4*4+2][lr] = sv4.z; sT[lc4*4+3][lr] = sv4.w;
    *(float4*)&wt[lr][lc4*4] = wv4;
    __syncthreads();

    float a00 = 0.f, a01 = 0.f, a10 = 0.f, a11 = 0.f;

    for (int it = 0; it < 12; ++it) {
        if (it < 11) {
            const int k0 = (it + 1) * 32;
            sv4 = *(const float4*)&s[(n0 + lr) * CSD + k0 + lc4 * 4];
            wv4 = *(const float4*)&wcat[(k0 + lr) * 1152 + ct * 32 + lc4 * 4];
        }
        #pragma unroll
        for (int kx = 0; kx < 32; ++kx) {
            float2 ss = *(const float2*)&sT[kx][tr * 2];
            float2 ww = *(const float2*)&wt[kx][tc * 2];
            a00 += ss.x * ww.x; a01 += ss.x * ww.y;
            a10 += ss.y * ww.x; a11 += ss.y * ww.y;
        }
        __syncthreads();
        if (it < 11) {
            sT[lc4*4+0][lr] = sv4.x; sT[lc4*4+1][lr] = sv4.y; sT[lc4*4+2][lr] = sv4.z; sT[lc4*4+3][lr] = sv4.w;
            *(float4*)&wt[lr][lc4*4] = wv4;
            __syncthreads();
        }
    }

    float accv[2][2] = {{a00, a01}, {a10, a11}};
    #pragma unroll
    for (int i = 0; i < 2; ++i) {
        const int n = n0 + tr * 2 + i;
        #pragma unroll
        for (int j = 0; j < 2; ++j) {
            const int gcol = ct * 32 + tc * 2 + j;
            const float v = accv[i][j] + bcat[gcol];
            if (gcol < 192) {
                q[n*192 + gcol] = v;
            } else if (gcol < 576) {
                int g = gcol - 192, h = g >> 5, cc = g & 31;
                if (cc < 16) kkT[(h*16 + cc)*NRES + n] = v;
                else         vcomb[n*NRES + h*16 + (cc-16)] = v;
            } else if (gcol < 720) {
                praw_q[n*144 + (gcol - 576)] = v;
            } else {
                praw_kv[n*432 + (gcol - 720)] = v;
            }
        }
    }
}

// ---------------------------------------------------------------- rigid-frame rotation
__global__ __launch_bounds__(256) void k_rot(
    const float* __restrict__ praw_q, const float* __restrict__ praw_kv,
    const float* __restrict__ rot, const float* __restrict__ trans,
    float* __restrict__ q_pts, float* __restrict__ kptsT, float* __restrict__ vcomb)
{
    const int idx = blockIdx.x * 256 + threadIdx.x;
    const int n = idx / 192, u = idx % 192;
    const float* R = rot + n*9;
    const float* T = trans + n*3;
    float px, py, pz;
    if (u < 48) {
        px = praw_q[n*144 + u]; py = praw_q[n*144 + 48 + u]; pz = praw_q[n*144 + 96 + u];
    } else {
        int pt = u - 48;
        px = praw_kv[n*432 + pt]; py = praw_kv[n*432 + 144 + pt]; pz = praw_kv[n*432 + 288 + pt];
    }
    float x  = R[0]*px + R[1]*py + R[2]*pz + T[0];
    float y  = R[3]*px + R[4]*py + R[5]*pz + T[1];
    float zc = R[6]*px + R[7]*py + R[8]*pz + T[2];
    if (u < 48) {
        int o = (n*48 + u)*3;
        q_pts[o] = x; q_pts[o+1] = y; q_pts[o+2] = zc;
    } else {
        int pt = u - 48;
        int h = pt / 12, pp = pt % 12;
        if (pp < 4) {
            int dim = (h*4 + pp)*3;
            kptsT[(dim+0)*NRES + n] = x;
            kptsT[(dim+1)*NRES + n] = y;
            kptsT[(dim+2)*NRES + n] = zc;
        } else {
            int u2 = (h*8 + (pp-4))*3;
            vcomb[n*NRES + 192 + u2+0] = x;
            vcomb[n*NRES + 192 + u2+1] = y;
            vcomb[n*NRES + 192 + u2+2] = zc;
        }
    }
}

// ---------------------------------------------------------------- fused per-q-row: bias+logits+softmax+o_pair+o/o_pt+rot
__global__ __launch_bounds__(256) void k_row(
    const float* __restrict__ z,
    const float* __restrict__ q, const float* __restrict__ kkT, const float* __restrict__ vcomb,
    const float* __restrict__ q_pts, const float* __restrict__ kptsT,
    const float* __restrict__ w_b, const float* __restrict__ b_b,
    const float* __restrict__ head_weights, const float* __restrict__ mask,
    const float* __restrict__ rot, const float* __restrict__ trans,
    float* __restrict__ o_cat)
{
    const int qn = blockIdx.x;
    const int t = threadIdx.x;

    __shared__ float zt[64*129];          // bias staging; later aliased as pair partials [4][12][128]
    __shared__ float wb[128*12];
    __shared__ float part[4][64][13];
    __shared__ float a_lds[12][520];
    __shared__ float q_lds[192];
    __shared__ float qp_lds[144];
    __shared__ float hw_lds[12];
    __shared__ float optraw[288];

    // preload small stuff
    for (int i = t; i < 1536; i += 256) wb[i] = w_b[i];
    if (t < 192) q_lds[t] = q[qn*192 + t];
    if (t < 144) qp_lds[t] = q_pts[qn*144 + t];
    if (t < 12)  hw_lds[t] = logf(1.f + expf(head_weights[t])) * 0.13608276f;

    // ---- phase 1: bias row (z first pass, HBM)
    const int kx = t & 63, qr = t >> 6;
    for (int kt = 0; kt < 8; ++kt) {
        const int k0 = kt*64;
        __syncthreads();
        const float4* zp4 = (const float4*)(z + ((size_t)qn*NRES + k0)*CZD);
        #pragma unroll
        for (int r = 0; r < 8; ++r) {
            int idx = t + r*256;
            int kk2 = idx >> 5, c4 = idx & 31;
            float4 v4 = zp4[idx];
            float* dst = &zt[kk2*129 + c4*4];
            dst[0]=v4.x; dst[1]=v4.y; dst[2]=v4.z; dst[3]=v4.w;
        }
        __syncthreads();
        float acc[12];
        #pragma unroll
        for (int h = 0; h < 12; ++h) acc[h] = 0.f;
        const float* zrow = &zt[kx*129 + qr*32];
        const float* wbp = &wb[qr*32*12];
        for (int c = 0; c < 32; ++c) {
            float zv = zrow[c];
            #pragma unroll
            for (int h = 0; h < 12; ++h) acc[h] += zv * wbp[c*12+h];
        }
        #pragma unroll
        for (int h = 0; h < 12; ++h) part[qr][kx][h] = acc[h];
        __syncthreads();
        for (int d = t; d < 768; d += 256) {
            int h = d >> 6, k2 = d & 63;
            a_lds[h][k0+k2] = b_b[h] + part[0][k2][h] + part[1][k2][h]
                            + part[2][k2][h] + part[3][k2][h];
        }
    }
    __syncthreads();

    // ---- phase 2: logits (in-place over a_lds)
    const float mq = mask[qn];
    for (int h = 0; h < 12; ++h) {
        float qv[16], qpv[12];
        #pragma unroll
        for (int c = 0; c < 16; ++c) qv[c] = q_lds[h*16+c];
        #pragma unroll
        for (int d = 0; d < 12; ++d) qpv[d] = qp_lds[h*12+d];
        const float hw = hw_lds[h];
        const float* kT  = kkT + h*16*NRES;
        const float* kpT = kptsT + h*12*NRES;
        #pragma unroll
        for (int r = 0; r < 2; ++r) {
            const int kn = t + r*256;
            float acc = 0.f;
            #pragma unroll
            for (int c = 0; c < 16; ++c) acc += qv[c] * kT[c*NRES + kn];
            acc *= 0.14433757f;
            acc += 0.57735027f * a_lds[h][kn];
            float dsum = 0.f;
            #pragma unroll
            for (int d = 0; d < 12; ++d) { float df = qpv[d] - kpT[d*NRES + kn]; dsum += df*df; }
            a_lds[h][kn] = acc - 0.5f*hw*dsum + (mq*mask[kn]-1.f)*100000.f;
        }
    }
    __syncthreads();

    // ---- phase 3: softmax, warp-parallel across heads (3 heads/warp)
    {
        const int w = t >> 6, lane = t & 63;
        for (int h = w; h < 12; h += 4) {
            float m = -1e30f;
            #pragma unroll
            for (int i = 0; i < 8; ++i) m = fmaxf(m, a_lds[h][lane + i*64]);
            #pragma unroll
            for (int off = 32; off > 0; off >>= 1) m = fmaxf(m, __shfl_xor(m, off));
            float ss = 0.f;
            #pragma unroll
            for (int i = 0; i < 8; ++i) {
                float e = __expf(a_lds[h][lane + i*64] - m);
                a_lds[h][lane + i*64] = e;
                ss += e;
            }
            #pragma unroll
            for (int off = 32; off > 0; off >>= 1) ss += __shfl_xor(ss, off);
            float inv = 1.f / ss;
            #pragma unroll
            for (int i = 0; i < 8; ++i) a_lds[h][lane + i*64] *= inv;
        }
    }
    __syncthreads();

    // ---- phase 4: o_pair (z second pass, L3-resident)
    {
        const int c4 = t & 31, kgrp = t >> 5;
        const float4* zp = (const float4*)(z + (size_t)qn*NRES*CZD) + c4;
        float4 acc4[12];
        #pragma unroll
        for (int h = 0; h < 12; ++h) acc4[h] = make_float4(0.f,0.f,0.f,0.f);

        #pragma unroll 4
        for (int kn = kgrp; kn < NRES; kn += 8) {
            float4 zv = zp[kn*32];
            #pragma unroll
            for (int h = 0; h < 12; ++h) {
                float av = a_lds[h][kn];
                acc4[h].x += av*zv.x; acc4[h].y += av*zv.y;
                acc4[h].z += av*zv.z; acc4[h].w += av*zv.w;
            }
        }
        #pragma unroll
        for (int h = 0; h < 12; ++h) {
            acc4[h].x += __shfl_xor(acc4[h].x, 32);
            acc4[h].y += __shfl_xor(acc4[h].y, 32);
            acc4[h].z += __shfl_xor(acc4[h].z, 32);
            acc4[h].w += __shfl_xor(acc4[h].w, 32);
        }
        float (*ppart)[12][128] = (float (*)[12][128])zt;   // alias dead z-tile
        const int wave = t >> 6;
        if ((t & 63) < 32) {
            #pragma unroll
            for (int h = 0; h < 12; ++h) {
                ppart[wave][h][c4*4+0] = acc4[h].x;
                ppart[wave][h][c4*4+1] = acc4[h].y;
                ppart[wave][h][c4*4+2] = acc4[h].z;
                ppart[wave][h][c4*4+3] = acc4[h].w;
            }
        }
        __syncthreads();
        for (int i = t; i < 1536; i += 256) {
            int h = i >> 7, c = i & 127;
            float v = ppart[0][h][c] + ppart[1][h][c] + ppart[2][h][c] + ppart[3][h][c];
            o_cat[qn*2112 + 576 + h*128 + c] = v;
        }
    }

    // ---- phase 5: o (192) + o_pt raw (288) from vcomb (L2-resident)
    {
        const int u0 = t;
        const int h0 = (u0 < 192) ? (u0 >> 4) : (u0 - 192) / 24;
        const int u1v = (t < 224) ? (t + 256) : 479;          // clamp in-bounds
        const int h1 = (u1v - 192) / 24;
        float acc0 = 0.f, acc1 = 0.f;
        const float* vp = vcomb;
        #pragma unroll 8
        for (int kn = 0; kn < NRES; ++kn) {
            const float* row = vp + (size_t)kn*NRES;
            acc0 += a_lds[h0][kn] * row[u0];
            acc1 += a_lds[h1][kn] * row[u1v];
        }
        if (u0 < 192) o_cat[qn*2112 + u0] = acc0;
        else          optraw[u0 - 192] = acc0;
        if (t < 224)  optraw[t + 64] = acc1;
    }
    __syncthreads();

    // ---- phase 6: inverse rotation + norms
    if (t < 96) {
        const float* R = rot + qn*9;
        const float* T = trans + qn*3;
        float ox = optraw[t*3]   - T[0];
        float oy = optraw[t*3+1] - T[1];
        float oz = optraw[t*3+2] - T[2];
        float x  = R[0]*ox + R[3]*oy + R[6]*oz;
        float y  = R[1]*ox + R[4]*oy + R[7]*oz;
        float zc = R[2]*ox + R[5]*oy + R[8]*oz;
        float* ob = o_cat + qn*2112;
        ob[192 + t] = x;
        ob[288 + t] = y;
        ob[384 + t] = zc;
        ob[480 + t] = sqrtf(x*x + y*y + zc*zc + 1e-8f);
    }
}

// ---------------------------------------------------------------- final GEMM
__global__ __launch_bounds__(256) void k_out2(
    const float* __restrict__ o_cat, const float* __restrict__ w_out, float* __restrict__ part)
{
    const int ct = blockIdx.x;
    const int n0 = blockIdx.y * 32;
    const int kc = blockIdx.z;
    const int t = threadIdx.x;

    __shared__ float oT[32][34];
    __shared__ float wt[32][36];

    const int lr = t >> 3, lc4 = t & 7;
    const int tr = t >> 4, tc = t & 15;
    const int kbase = kc * 352;
    float4 ov4, wv4;

    ov4 = *(const float4*)&o_cat[(n0 + lr) * 2112 + kbase + lc4 * 4];
    wv4 = *(const float4*)&w_out[(kbase + lr) * 384 + ct * 32 + lc4 * 4];
    oT[lc4*4+0][lr] = ov4.x; oT[lc4*4+1][lr] = ov4.y; oT[lc4*4+2][lr] = ov4.z; oT[lc4*4+3][lr] = ov4.w;
    *(float4*)&wt[lr][lc4*4] = wv4;
    __syncthreads();

    float a00 = 0.f, a01 = 0.f, a10 = 0.f, a11 = 0.f;

    for (int it = 0; it < 11; ++it) {
        if (it < 10) {
            const int k0 = kbase + (it + 1) * 32;
            ov4 = *(const float4*)&o_cat[(n0 + lr) * 2112 + k0 + lc4 * 4];
            wv4 = *(const float4*)&w_out[(k0 + lr) * 384 + ct * 32 + lc4 * 4];
        }
        #pragma unroll
        for (int kx = 0; kx < 32; ++kx) {
            float2 oo = *(const float2*)&oT[kx][tr * 2];
            float2 ww = *(const float2*)&wt[kx][tc * 2];
            a00 += oo.x * ww.x; a01 += oo.x * ww.y;
            a10 += oo.y * ww.x; a11 += oo.y * ww.y;
        }
        __syncthreads();
        if (it < 10) {
            oT[lc4*4+0][lr] = ov4.x; oT[lc4*4+1][lr] = ov4.y; oT[lc4*4+2][lr] = ov4.z; oT[lc4*4+3][lr] = ov4.w;
            *(float4*)&wt[lr][lc4*4] = wv4;
            __syncthreads();
        }
    }

    float* pp = part + (size_t)kc * 196608;
    pp[(n0 + tr*2 + 0)*384 + ct*32 + tc*2 + 0] = a00;
    pp[(n0 + tr*2 + 0)*384 + ct*32 + tc*2 + 1] = a01;
    pp[(n0 + tr*2 + 1)*384 + ct*32 + tc*2 + 0] = a10;
    pp[(n0 + tr*2 + 1)*384 + ct*32 + tc*2 + 1] = a11;
}

__global__ __launch_bounds__(256) void k_red(
    const float* __restrict__ part, const float* __restrict__ b_out, float* __restrict__ out)
{
    const int i = blockIdx.x*256 + threadIdx.x;
    float acc = b_out[i % 384];
    #pragma unroll
    for (int dc = 0; dc < 6; ++dc) acc += part[(size_t)dc*196608 + i];
    out[i] = acc;
}

// ----------------------------------------------------------------
extern "C" void kernel_launch(void* const* d_in, const int* in_sizes, int n_in,
                              void* d_out, int out_size, void* d_ws, size_t ws_size,
                              hipStream_t stream) {
    (void)in_sizes; (void)n_in; (void)out_size; (void)ws_size;
    const float* s      = (const float*)d_in[0];
    const float* z      = (const float*)d_in[1];
    const float* rot    = (const float*)d_in[2];
    const float* trans  = (const float*)d_in[3];
    const float* mask   = (const float*)d_in[4];
    const float* w_q    = (const float*)d_in[5];
    const float* b_q    = (const float*)d_in[6];
    const float* w_kv   = (const float*)d_in[7];
    const float* b_kv   = (const float*)d_in[8];
    const float* w_qp   = (const float*)d_in[9];
    const float* b_qp   = (const float*)d_in[10];
    const float* w_kvp  = (const float*)d_in[11];
    const float* b_kvp  = (const float*)d_in[12];
    const float* w_b    = (const float*)d_in[13];
    const float* b_b    = (const float*)d_in[14];
    const float* hwts   = (const float*)d_in[15];
    const float* w_out  = (const float*)d_in[16];
    const float* b_out  = (const float*)d_in[17];
    float* out = (float*)d_out;
    float* ws  = (float*)d_ws;

    float* q      = ws + OFF_Q;
    float* kkT    = ws + OFF_KT;
    float* vcomb  = ws + OFF_VC;
    float* qp     = ws + OFF_QP;
    float* kptsT  = ws + OFF_KPT;
    float* ocat   = ws + OFF_OCAT;
    float* wcat   = ws + OFF_WCAT;
    float* bcat   = ws + OFF_BCAT;
    float* part   = ws + OFF_PART;
    float* praw_q  = ws + OFF_PRAWQ;
    float* praw_kv = ws + OFF_PRAWK;

    k_wcat<<<dim3(1733), dim3(256), 0, stream>>>(w_q, b_q, w_kv, b_kv, w_qp, b_qp, w_kvp, b_kvp, wcat, bcat);
    k_proj2<<<dim3(36, 16), dim3(256), 0, stream>>>(s, wcat, bcat, q, kkT, vcomb, praw_q, praw_kv);
    k_rot<<<dim3(384), dim3(256), 0, stream>>>(praw_q, praw_kv, rot, trans, qp, kptsT, vcomb);
    k_row<<<dim3(NRES), dim3(256), 0, stream>>>(z, q, kkT, vcomb, qp, kptsT,
        w_b, b_b, hwts, mask, rot, trans, ocat);
    k_out2<<<dim3(12, 16, 6), dim3(256), 0, stream>>>(ocat, w_out, part);
    k_red<<<dim3(768), dim3(256), 0, stream>>>(part, b_out, out);
}